// Round 1
// baseline (462.082 us; speedup 1.0000x reference)
//
#include <hip/hip_runtime.h>
#include <hip/hip_bf16.h>

// ---------------------------------------------------------------------------
// GATConv (PyG-style, H=2 heads, C=64, concat=False -> head mean) on gfx950.
// Phases:
//   1. k_gemm   : h = x@W  (fp32, W in LDS), fused per-node logits a_s, a_d
//   2. k_hist/scan/scatter : build CSR of edges grouped by destination
//   3. k_aggr   : per-dst wave: online softmax over incoming edges (+self
//                 loop), then alpha-weighted gather-accumulate of h rows.
// ---------------------------------------------------------------------------

__global__ __launch_bounds__(256) void k_zero(int* __restrict__ p, int n) {
  int i = blockIdx.x * 256 + threadIdx.x;
  if (i < n) p[i] = 0;
}

// h = x @ W  (x: [N,128], W: [128,128]), plus a_s[n][h], a_d[n][h]
__global__ __launch_bounds__(256) void k_gemm(
    const float* __restrict__ x, const float* __restrict__ W,
    const float* __restrict__ att_s, const float* __restrict__ att_d,
    float* __restrict__ h, float* __restrict__ a_s, float* __restrict__ a_d,
    int Nn) {
  __shared__ float Wl[128 * 128];  // 64 KB
  {
    const float4* W4 = (const float4*)W;
    float4* Wl4 = (float4*)Wl;
    for (int i = threadIdx.x; i < 4096; i += 256) Wl4[i] = W4[i];
  }
  __syncthreads();
  const int wave = threadIdx.x >> 6;
  const int lane = threadIdx.x & 63;
  const int c0 = lane * 2;  // flattened H*C channel pair (c0, c0+1)
  const float as0 = att_s[c0], as1 = att_s[c0 + 1];
  const float ad0 = att_d[c0], ad1 = att_d[c0 + 1];
  const int ngroups = (Nn + 3) >> 2;
  for (int g = blockIdx.x * 4 + wave; g < ngroups; g += gridDim.x * 4) {
    const int row0 = g * 4;
    const int nr = (Nn - row0 < 4) ? (Nn - row0) : 4;
    float acc[4][2];
#pragma unroll
    for (int r = 0; r < 4; ++r) { acc[r][0] = 0.f; acc[r][1] = 0.f; }
    for (int kk = 0; kk < 32; ++kk) {
      float4 xv[4];
#pragma unroll
      for (int r = 0; r < 4; ++r) {
        int rr = row0 + r; rr = (rr < Nn) ? rr : (Nn - 1);  // clamp, no OOB
        xv[r] = *(const float4*)&x[(size_t)rr * 128 + kk * 4];
      }
#pragma unroll
      for (int j = 0; j < 4; ++j) {
        float2 w2 = *(const float2*)&Wl[(kk * 4 + j) * 128 + c0];
#pragma unroll
        for (int r = 0; r < 4; ++r) {
          float f = (&xv[r].x)[j];
          acc[r][0] = fmaf(f, w2.x, acc[r][0]);
          acc[r][1] = fmaf(f, w2.y, acc[r][1]);
        }
      }
    }
    for (int r = 0; r < nr; ++r) {
      const int row = row0 + r;
      *(float2*)&h[(size_t)row * 128 + c0] = make_float2(acc[r][0], acc[r][1]);
      float ps = acc[r][0] * as0 + acc[r][1] * as1;
      float pd = acc[r][0] * ad0 + acc[r][1] * ad1;
#pragma unroll
      for (int m = 1; m <= 16; m <<= 1) {
        ps += __shfl_xor(ps, m, 64);
        pd += __shfl_xor(pd, m, 64);
      }
      if (lane == 0)  { a_s[row * 2 + 0] = ps; a_d[row * 2 + 0] = pd; }
      if (lane == 32) { a_s[row * 2 + 1] = ps; a_d[row * 2 + 1] = pd; }
    }
  }
}

__global__ __launch_bounds__(256) void k_hist(const int* __restrict__ dst,
                                              int* __restrict__ cnt, int E) {
  for (int i = blockIdx.x * blockDim.x + threadIdx.x; i < E;
       i += gridDim.x * blockDim.x)
    atomicAdd(&cnt[dst[i]], 1);
}

__global__ __launch_bounds__(256) void k_scan1(const int* __restrict__ cnt,
                                               int* __restrict__ off,
                                               int* __restrict__ bsum, int n) {
  __shared__ int tmp[256];
  const int t = threadIdx.x;
  const int idx = blockIdx.x * 256 + t;
  int v = (idx < n) ? cnt[idx] : 0;
  tmp[t] = v;
  __syncthreads();
  for (int d = 1; d < 256; d <<= 1) {
    int add = (t >= d) ? tmp[t - d] : 0;
    __syncthreads();
    tmp[t] += add;
    __syncthreads();
  }
  if (idx < n) off[idx] = tmp[t] - v;  // exclusive
  if (t == 255) bsum[blockIdx.x] = tmp[255];
}

__global__ __launch_bounds__(256) void k_scan2(int* __restrict__ bsum, int nb) {
  __shared__ int tmp[256];
  const int t = threadIdx.x;
  int v = (t < nb) ? bsum[t] : 0;
  tmp[t] = v;
  __syncthreads();
  for (int d = 1; d < 256; d <<= 1) {
    int add = (t >= d) ? tmp[t - d] : 0;
    __syncthreads();
    tmp[t] += add;
    __syncthreads();
  }
  if (t < nb) bsum[t] = tmp[t] - v;  // exclusive
}

__global__ __launch_bounds__(256) void k_scan3(int* __restrict__ off,
                                               const int* __restrict__ bsum,
                                               int* __restrict__ cursor, int n) {
  const int idx = blockIdx.x * 256 + threadIdx.x;
  if (idx < n) {
    int o = off[idx] + bsum[blockIdx.x];
    off[idx] = o;
    cursor[idx] = o;
  }
}

__global__ __launch_bounds__(256) void k_scatter(const int* __restrict__ src,
                                                 const int* __restrict__ dst,
                                                 int* __restrict__ cursor,
                                                 int* __restrict__ csr, int E) {
  for (int i = blockIdx.x * blockDim.x + threadIdx.x; i < E;
       i += gridDim.x * blockDim.x) {
    int d = dst[i];
    int p = atomicAdd(&cursor[d], 1);
    csr[p] = src[i];
  }
}

__device__ __forceinline__ float leaky02(float v) {
  return v > 0.f ? v : 0.2f * v;
}

// One wave per destination node.
__global__ __launch_bounds__(256) void k_aggr(
    const float* __restrict__ h, const float* __restrict__ a_s,
    const float* __restrict__ a_d, const int* __restrict__ off,
    const int* __restrict__ cnt, const int* __restrict__ csr,
    const float* __restrict__ bias, float* __restrict__ out, int Nn) {
  const int wave = threadIdx.x >> 6;
  const int lane = threadIdx.x & 63;
  const int d = blockIdx.x * 4 + wave;
  if (d >= Nn) return;
  const int o = off[d];
  const int deg = cnt[d];
  const float ad0 = a_d[d * 2 + 0], ad1 = a_d[d * 2 + 1];
  const float NEG = -1e30f;
  float m0 = NEG, s0 = 0.f, m1 = NEG, s1 = 0.f;
  // Pass A: lane-parallel online max/sum of exp(leaky(logit)) per head
  for (int e = lane; e < deg; e += 64) {
    int s = csr[o + e];
    float l0 = leaky02(a_s[s * 2 + 0] + ad0);
    float l1 = leaky02(a_s[s * 2 + 1] + ad1);
    float nm = fmaxf(m0, l0);
    s0 = s0 * __expf(m0 - nm) + __expf(l0 - nm); m0 = nm;
    nm = fmaxf(m1, l1);
    s1 = s1 * __expf(m1 - nm) + __expf(l1 - nm); m1 = nm;
  }
#pragma unroll
  for (int msk = 1; msk <= 32; msk <<= 1) {
    float om = __shfl_xor(m0, msk, 64), os = __shfl_xor(s0, msk, 64);
    float nm = fmaxf(m0, om);
    s0 = s0 * __expf(m0 - nm) + os * __expf(om - nm); m0 = nm;
    om = __shfl_xor(m1, msk, 64); os = __shfl_xor(s1, msk, 64);
    nm = fmaxf(m1, om);
    s1 = s1 * __expf(m1 - nm) + os * __expf(om - nm); m1 = nm;
  }
  {  // self loop
    float l0 = leaky02(a_s[d * 2 + 0] + ad0);
    float l1 = leaky02(a_s[d * 2 + 1] + ad1);
    float nm = fmaxf(m0, l0);
    s0 = s0 * __expf(m0 - nm) + __expf(l0 - nm); m0 = nm;
    nm = fmaxf(m1, l1);
    s1 = s1 * __expf(m1 - nm) + __expf(l1 - nm); m1 = nm;
  }
  const float msel = (lane < 32) ? m0 : m1;
  const float invsel = 1.f / (((lane < 32) ? s0 : s1) + 1e-16f);
  const float adsel = (lane < 32) ? ad0 : ad1;
  const int hsel = lane >> 5;   // head of this lane's channels
  const int c0 = lane * 2;      // flattened H*C channel pair
  float acc0 = 0.f, acc1 = 0.f;
  // Pass B: serial over edges; lanes own 2 contiguous channels each
  for (int e = 0; e < deg; ++e) {
    int s = csr[o + e];  // wave-uniform load
    float lg = leaky02(a_s[s * 2 + hsel] + adsel);
    float alpha = __expf(lg - msel) * invsel;
    float2 hv = *(const float2*)&h[(size_t)s * 128 + c0];
    acc0 = fmaf(alpha, hv.x, acc0);
    acc1 = fmaf(alpha, hv.y, acc1);
  }
  {  // self loop
    float lg = leaky02(a_s[d * 2 + hsel] + adsel);
    float alpha = __expf(lg - msel) * invsel;
    float2 hv = *(const float2*)&h[(size_t)d * 128 + c0];
    acc0 = fmaf(alpha, hv.x, acc0);
    acc1 = fmaf(alpha, hv.y, acc1);
  }
  // head mean: lane l (<32, head0 ch 2l,2l+1) + lane l+32 (head1 ch 2l,2l+1)
  float o0 = acc0 + __shfl_down(acc0, 32, 64);
  float o1 = acc1 + __shfl_down(acc1, 32, 64);
  if (lane < 32) {
    int c = lane * 2;
    float2 res = make_float2(0.5f * o0 + bias[c], 0.5f * o1 + bias[c + 1]);
    *(float2*)&out[(size_t)d * 64 + c] = res;
  }
}

extern "C" void kernel_launch(void* const* d_in, const int* in_sizes, int n_in,
                              void* d_out, int out_size, void* d_ws,
                              size_t ws_size, hipStream_t stream) {
  const float* x = (const float*)d_in[0];
  const float* W = (const float*)d_in[1];
  const float* att_s = (const float*)d_in[2];
  const float* att_d = (const float*)d_in[3];
  const float* bias = (const float*)d_in[4];
  const int* ei = (const int*)d_in[5];
  const int Nn = in_sizes[0] / 128;
  const int E = in_sizes[5] / 2;
  const int* src = ei;
  const int* dst = ei + E;
  float* out = (float*)d_out;

  // workspace layout
  float* h = (float*)d_ws;                     // N*128
  float* a_s = h + (size_t)Nn * 128;           // N*2
  float* a_d = a_s + (size_t)Nn * 2;           // N*2
  int* cnt = (int*)(a_d + (size_t)Nn * 2);     // N
  int* off = cnt + Nn;                         // N
  int* cursor = off + Nn;                      // N
  int* bsum = cursor + Nn;                     // 256
  int* csr = bsum + 256;                       // E

  const int nb = (Nn + 255) / 256;  // 196 for N=50000 (fits k_scan2's 256)

  hipLaunchKernelGGL(k_zero, dim3(nb), dim3(256), 0, stream, cnt, Nn);
  hipLaunchKernelGGL(k_gemm, dim3(512), dim3(256), 0, stream, x, W, att_s,
                     att_d, h, a_s, a_d, Nn);
  hipLaunchKernelGGL(k_hist, dim3(1024), dim3(256), 0, stream, dst, cnt, E);
  hipLaunchKernelGGL(k_scan1, dim3(nb), dim3(256), 0, stream, cnt, off, bsum,
                     Nn);
  hipLaunchKernelGGL(k_scan2, dim3(1), dim3(256), 0, stream, bsum, nb);
  hipLaunchKernelGGL(k_scan3, dim3(nb), dim3(256), 0, stream, off, bsum,
                     cursor, Nn);
  hipLaunchKernelGGL(k_scatter, dim3(1024), dim3(256), 0, stream, src, dst,
                     cursor, csr, E);
  hipLaunchKernelGGL(k_aggr, dim3((Nn + 3) / 4), dim3(256), 0, stream, h, a_s,
                     a_d, off, cnt, csr, bias, out, Nn);
}

// Round 2
// 354.890 us; speedup vs baseline: 1.3020x; 1.3020x over previous
//
#include <hip/hip_runtime.h>
#include <hip/hip_bf16.h>

// ---------------------------------------------------------------------------
// GATConv (PyG-style, H=2 heads, C=64, concat=False -> head mean) on gfx950.
// Phases:
//   1. k_gemm   : h = x@W (fp32 math, W in LDS), h stored as bf16 (read ~33x
//                 by the gather; bf16 halves gather bytes, error ~0.01 vs
//                 2.78e-2 threshold). Fused per-node logits a_s, a_d (fp32).
//   2. k_hist/scan/scatter : build CSR of edges grouped by destination
//   3. k_aggr   : per-dst wave: online softmax over incoming edges (+self
//                 loop), then alpha-weighted gather-accumulate of bf16 h rows
//                 (4-deep unrolled for load-level parallelism).
// ---------------------------------------------------------------------------

__global__ __launch_bounds__(256) void k_zero(int* __restrict__ p, int n) {
  int i = blockIdx.x * 256 + threadIdx.x;
  if (i < n) p[i] = 0;
}

// h = x @ W  (x: [N,128], W: [128,128]) -> bf16 h, plus fp32 a_s[n][h], a_d[n][h]
__global__ __launch_bounds__(256) void k_gemm(
    const float* __restrict__ x, const float* __restrict__ W,
    const float* __restrict__ att_s, const float* __restrict__ att_d,
    __hip_bfloat162* __restrict__ h2, float* __restrict__ a_s,
    float* __restrict__ a_d, int Nn) {
  __shared__ float Wl[128 * 128];  // 64 KB
  {
    const float4* W4 = (const float4*)W;
    float4* Wl4 = (float4*)Wl;
    for (int i = threadIdx.x; i < 4096; i += 256) Wl4[i] = W4[i];
  }
  __syncthreads();
  const int wave = threadIdx.x >> 6;
  const int lane = threadIdx.x & 63;
  const int c0 = lane * 2;  // flattened H*C channel pair (c0, c0+1)
  const float as0 = att_s[c0], as1 = att_s[c0 + 1];
  const float ad0 = att_d[c0], ad1 = att_d[c0 + 1];
  const int ngroups = (Nn + 3) >> 2;
  for (int g = blockIdx.x * 4 + wave; g < ngroups; g += gridDim.x * 4) {
    const int row0 = g * 4;
    const int nr = (Nn - row0 < 4) ? (Nn - row0) : 4;
    float acc[4][2];
#pragma unroll
    for (int r = 0; r < 4; ++r) { acc[r][0] = 0.f; acc[r][1] = 0.f; }
    for (int kk = 0; kk < 32; ++kk) {
      float4 xv[4];
#pragma unroll
      for (int r = 0; r < 4; ++r) {
        int rr = row0 + r; rr = (rr < Nn) ? rr : (Nn - 1);  // clamp, no OOB
        xv[r] = *(const float4*)&x[(size_t)rr * 128 + kk * 4];
      }
#pragma unroll
      for (int j = 0; j < 4; ++j) {
        float2 w2 = *(const float2*)&Wl[(kk * 4 + j) * 128 + c0];
#pragma unroll
        for (int r = 0; r < 4; ++r) {
          float f = (&xv[r].x)[j];
          acc[r][0] = fmaf(f, w2.x, acc[r][0]);
          acc[r][1] = fmaf(f, w2.y, acc[r][1]);
        }
      }
    }
    for (int r = 0; r < nr; ++r) {
      const int row = row0 + r;
      __hip_bfloat162 hv;
      hv.x = __float2bfloat16(acc[r][0]);
      hv.y = __float2bfloat16(acc[r][1]);
      h2[(size_t)row * 64 + lane] = hv;
      float ps = acc[r][0] * as0 + acc[r][1] * as1;
      float pd = acc[r][0] * ad0 + acc[r][1] * ad1;
#pragma unroll
      for (int m = 1; m <= 16; m <<= 1) {
        ps += __shfl_xor(ps, m, 64);
        pd += __shfl_xor(pd, m, 64);
      }
      if (lane == 0)  { a_s[row * 2 + 0] = ps; a_d[row * 2 + 0] = pd; }
      if (lane == 32) { a_s[row * 2 + 1] = ps; a_d[row * 2 + 1] = pd; }
    }
  }
}

__global__ __launch_bounds__(256) void k_hist(const int* __restrict__ dst,
                                              int* __restrict__ cnt, int E) {
  for (int i = blockIdx.x * blockDim.x + threadIdx.x; i < E;
       i += gridDim.x * blockDim.x)
    atomicAdd(&cnt[dst[i]], 1);
}

__global__ __launch_bounds__(256) void k_scan1(const int* __restrict__ cnt,
                                               int* __restrict__ off,
                                               int* __restrict__ bsum, int n) {
  __shared__ int tmp[256];
  const int t = threadIdx.x;
  const int idx = blockIdx.x * 256 + t;
  int v = (idx < n) ? cnt[idx] : 0;
  tmp[t] = v;
  __syncthreads();
  for (int d = 1; d < 256; d <<= 1) {
    int add = (t >= d) ? tmp[t - d] : 0;
    __syncthreads();
    tmp[t] += add;
    __syncthreads();
  }
  if (idx < n) off[idx] = tmp[t] - v;  // exclusive
  if (t == 255) bsum[blockIdx.x] = tmp[255];
}

__global__ __launch_bounds__(256) void k_scan2(int* __restrict__ bsum, int nb) {
  __shared__ int tmp[256];
  const int t = threadIdx.x;
  int v = (t < nb) ? bsum[t] : 0;
  tmp[t] = v;
  __syncthreads();
  for (int d = 1; d < 256; d <<= 1) {
    int add = (t >= d) ? tmp[t - d] : 0;
    __syncthreads();
    tmp[t] += add;
    __syncthreads();
  }
  if (t < nb) bsum[t] = tmp[t] - v;  // exclusive
}

__global__ __launch_bounds__(256) void k_scan3(int* __restrict__ off,
                                               const int* __restrict__ bsum,
                                               int* __restrict__ cursor, int n) {
  const int idx = blockIdx.x * 256 + threadIdx.x;
  if (idx < n) {
    int o = off[idx] + bsum[blockIdx.x];
    off[idx] = o;
    cursor[idx] = o;
  }
}

__global__ __launch_bounds__(256) void k_scatter(const int* __restrict__ src,
                                                 const int* __restrict__ dst,
                                                 int* __restrict__ cursor,
                                                 int* __restrict__ csr, int E) {
  for (int i = blockIdx.x * blockDim.x + threadIdx.x; i < E;
       i += gridDim.x * blockDim.x) {
    int d = dst[i];
    int p = atomicAdd(&cursor[d], 1);
    csr[p] = src[i];
  }
}

__device__ __forceinline__ float leaky02(float v) {
  return v > 0.f ? v : 0.2f * v;
}

// One wave per destination node.
__global__ __launch_bounds__(256) void k_aggr(
    const __hip_bfloat162* __restrict__ h2, const float* __restrict__ a_s,
    const float* __restrict__ a_d, const int* __restrict__ off,
    const int* __restrict__ cnt, const int* __restrict__ csr,
    const float* __restrict__ bias, float* __restrict__ out, int Nn) {
  const int wave = threadIdx.x >> 6;
  const int lane = threadIdx.x & 63;
  const int d = blockIdx.x * 4 + wave;
  if (d >= Nn) return;
  const int o = off[d];
  const int deg = cnt[d];
  const float ad0 = a_d[d * 2 + 0], ad1 = a_d[d * 2 + 1];
  const float NEG = -1e30f;
  float m0 = NEG, s0 = 0.f, m1 = NEG, s1 = 0.f;
  // Pass A: lane-parallel online max/sum of exp(leaky(logit)) per head
  for (int e = lane; e < deg; e += 64) {
    int s = csr[o + e];
    float l0 = leaky02(a_s[s * 2 + 0] + ad0);
    float l1 = leaky02(a_s[s * 2 + 1] + ad1);
    float nm = fmaxf(m0, l0);
    s0 = s0 * __expf(m0 - nm) + __expf(l0 - nm); m0 = nm;
    nm = fmaxf(m1, l1);
    s1 = s1 * __expf(m1 - nm) + __expf(l1 - nm); m1 = nm;
  }
#pragma unroll
  for (int msk = 1; msk <= 32; msk <<= 1) {
    float om = __shfl_xor(m0, msk, 64), os = __shfl_xor(s0, msk, 64);
    float nm = fmaxf(m0, om);
    s0 = s0 * __expf(m0 - nm) + os * __expf(om - nm); m0 = nm;
    om = __shfl_xor(m1, msk, 64); os = __shfl_xor(s1, msk, 64);
    nm = fmaxf(m1, om);
    s1 = s1 * __expf(m1 - nm) + os * __expf(om - nm); m1 = nm;
  }
  {  // self loop
    float l0 = leaky02(a_s[d * 2 + 0] + ad0);
    float l1 = leaky02(a_s[d * 2 + 1] + ad1);
    float nm = fmaxf(m0, l0);
    s0 = s0 * __expf(m0 - nm) + __expf(l0 - nm); m0 = nm;
    nm = fmaxf(m1, l1);
    s1 = s1 * __expf(m1 - nm) + __expf(l1 - nm); m1 = nm;
  }
  const float msel = (lane < 32) ? m0 : m1;
  const float invsel = 1.f / (((lane < 32) ? s0 : s1) + 1e-16f);
  const float adsel = (lane < 32) ? ad0 : ad1;
  const int hsel = lane >> 5;  // head of this lane's channels
  float acc0 = 0.f, acc1 = 0.f;
  // Pass B: serial over edges, 4-deep unrolled (4 gather chains in flight);
  // lanes own 2 contiguous channels each (4B bf16x2 per lane = 256B/wave/edge)
  int e = 0;
  for (; e + 4 <= deg; e += 4) {
    int sA = csr[o + e + 0], sB = csr[o + e + 1];
    int sC = csr[o + e + 2], sD = csr[o + e + 3];
    __hip_bfloat162 hA = h2[(size_t)sA * 64 + lane];
    __hip_bfloat162 hB = h2[(size_t)sB * 64 + lane];
    __hip_bfloat162 hC = h2[(size_t)sC * 64 + lane];
    __hip_bfloat162 hD = h2[(size_t)sD * 64 + lane];
    float lgA = leaky02(a_s[sA * 2 + hsel] + adsel);
    float lgB = leaky02(a_s[sB * 2 + hsel] + adsel);
    float lgC = leaky02(a_s[sC * 2 + hsel] + adsel);
    float lgD = leaky02(a_s[sD * 2 + hsel] + adsel);
    float aA = __expf(lgA - msel) * invsel;
    float aB = __expf(lgB - msel) * invsel;
    float aC = __expf(lgC - msel) * invsel;
    float aD = __expf(lgD - msel) * invsel;
    acc0 = fmaf(aA, __bfloat162float(hA.x), acc0);
    acc1 = fmaf(aA, __bfloat162float(hA.y), acc1);
    acc0 = fmaf(aB, __bfloat162float(hB.x), acc0);
    acc1 = fmaf(aB, __bfloat162float(hB.y), acc1);
    acc0 = fmaf(aC, __bfloat162float(hC.x), acc0);
    acc1 = fmaf(aC, __bfloat162float(hC.y), acc1);
    acc0 = fmaf(aD, __bfloat162float(hD.x), acc0);
    acc1 = fmaf(aD, __bfloat162float(hD.y), acc1);
  }
  for (; e < deg; ++e) {
    int s = csr[o + e];
    float lg = leaky02(a_s[s * 2 + hsel] + adsel);
    float alpha = __expf(lg - msel) * invsel;
    __hip_bfloat162 hv = h2[(size_t)s * 64 + lane];
    acc0 = fmaf(alpha, __bfloat162float(hv.x), acc0);
    acc1 = fmaf(alpha, __bfloat162float(hv.y), acc1);
  }
  {  // self loop
    float lg = leaky02(a_s[d * 2 + hsel] + adsel);
    float alpha = __expf(lg - msel) * invsel;
    __hip_bfloat162 hv = h2[(size_t)d * 64 + lane];
    acc0 = fmaf(alpha, __bfloat162float(hv.x), acc0);
    acc1 = fmaf(alpha, __bfloat162float(hv.y), acc1);
  }
  // head mean: lane l (<32, head0 ch 2l,2l+1) + lane l+32 (head1 ch 2l,2l+1)
  float o0 = acc0 + __shfl_down(acc0, 32, 64);
  float o1 = acc1 + __shfl_down(acc1, 32, 64);
  if (lane < 32) {
    int c = lane * 2;
    float2 res = make_float2(0.5f * o0 + bias[c], 0.5f * o1 + bias[c + 1]);
    *(float2*)&out[(size_t)d * 64 + c] = res;
  }
}

extern "C" void kernel_launch(void* const* d_in, const int* in_sizes, int n_in,
                              void* d_out, int out_size, void* d_ws,
                              size_t ws_size, hipStream_t stream) {
  const float* x = (const float*)d_in[0];
  const float* W = (const float*)d_in[1];
  const float* att_s = (const float*)d_in[2];
  const float* att_d = (const float*)d_in[3];
  const float* bias = (const float*)d_in[4];
  const int* ei = (const int*)d_in[5];
  const int Nn = in_sizes[0] / 128;
  const int E = in_sizes[5] / 2;
  const int* src = ei;
  const int* dst = ei + E;
  float* out = (float*)d_out;

  // workspace layout
  __hip_bfloat162* h2 = (__hip_bfloat162*)d_ws;        // N*64 (bf16x2)
  float* a_s = (float*)(h2 + (size_t)Nn * 64);         // N*2
  float* a_d = a_s + (size_t)Nn * 2;                   // N*2
  int* cnt = (int*)(a_d + (size_t)Nn * 2);             // N
  int* off = cnt + Nn;                                 // N
  int* cursor = off + Nn;                              // N
  int* bsum = cursor + Nn;                             // 256
  int* csr = bsum + 256;                               // E

  const int nb = (Nn + 255) / 256;  // 196 for N=50000 (fits k_scan2's 256)

  hipLaunchKernelGGL(k_zero, dim3(nb), dim3(256), 0, stream, cnt, Nn);
  hipLaunchKernelGGL(k_gemm, dim3(512), dim3(256), 0, stream, x, W, att_s,
                     att_d, h2, a_s, a_d, Nn);
  hipLaunchKernelGGL(k_hist, dim3(1024), dim3(256), 0, stream, dst, cnt, E);
  hipLaunchKernelGGL(k_scan1, dim3(nb), dim3(256), 0, stream, cnt, off, bsum,
                     Nn);
  hipLaunchKernelGGL(k_scan2, dim3(1), dim3(256), 0, stream, bsum, nb);
  hipLaunchKernelGGL(k_scan3, dim3(nb), dim3(256), 0, stream, off, bsum,
                     cursor, Nn);
  hipLaunchKernelGGL(k_scatter, dim3(1024), dim3(256), 0, stream, src, dst,
                     cursor, csr, E);
  hipLaunchKernelGGL(k_aggr, dim3((Nn + 3) / 4), dim3(256), 0, stream, h2, a_s,
                     a_d, off, cnt, csr, bias, out, Nn);
}

// Round 3
// 188.139 us; speedup vs baseline: 2.4561x; 1.8863x over previous
//
#include <hip/hip_runtime.h>
#include <hip/hip_bf16.h>

// ---------------------------------------------------------------------------
// GATConv (PyG-style, H=2 heads, C=64, concat=False -> head mean) on gfx950.
// Phases:
//   1. k_gemm   : h = x@W (fp32 math, W in LDS), h stored bf16; fused logits.
//   2. CSR build via two-level counting sort (no global atomics):
//        k_bhist  : per-chunk LDS histogram over 391 buckets (dst>>7)
//        k_bscan  : per-bucket exclusive scan over chunks -> raw cursors
//        k_bbase  : exclusive scan of bucket totals -> bucket bases
//        k_binsert: scatter packed (ldst<<16|src) into bucket-grouped pairs
//                   via private LDS cursors (writes line-dense, L2-local)
//        k_bucket : per-bucket block: LDS per-node count + scan -> off/cnt,
//                   then LDS-atomic scatter into csr (16KB L2-local window)
//   3. k_aggr   : per-dst wave: online softmax over incoming edges (+self
//                 loop), then alpha-weighted gather of bf16 h rows (4-deep).
// ---------------------------------------------------------------------------

#define NBLK 256   // edge chunks (= threads in k_bscan)
#define TH 512     // threads for bhist/binsert
#define BSH 7      // bucket = dst >> 7
#define BSZ 128    // nodes per bucket
#define MAXBUCK 512

// h = x @ W  (x: [N,128], W: [128,128]) -> bf16 h, plus fp32 a_s[n][h], a_d[n][h]
__global__ __launch_bounds__(256) void k_gemm(
    const float* __restrict__ x, const float* __restrict__ W,
    const float* __restrict__ att_s, const float* __restrict__ att_d,
    __hip_bfloat162* __restrict__ h2, float* __restrict__ a_s,
    float* __restrict__ a_d, int Nn) {
  __shared__ float Wl[128 * 128];  // 64 KB
  {
    const float4* W4 = (const float4*)W;
    float4* Wl4 = (float4*)Wl;
    for (int i = threadIdx.x; i < 4096; i += 256) Wl4[i] = W4[i];
  }
  __syncthreads();
  const int wave = threadIdx.x >> 6;
  const int lane = threadIdx.x & 63;
  const int c0 = lane * 2;
  const float as0 = att_s[c0], as1 = att_s[c0 + 1];
  const float ad0 = att_d[c0], ad1 = att_d[c0 + 1];
  const int ngroups = (Nn + 3) >> 2;
  for (int g = blockIdx.x * 4 + wave; g < ngroups; g += gridDim.x * 4) {
    const int row0 = g * 4;
    const int nr = (Nn - row0 < 4) ? (Nn - row0) : 4;
    float acc[4][2];
#pragma unroll
    for (int r = 0; r < 4; ++r) { acc[r][0] = 0.f; acc[r][1] = 0.f; }
    for (int kk = 0; kk < 32; ++kk) {
      float4 xv[4];
#pragma unroll
      for (int r = 0; r < 4; ++r) {
        int rr = row0 + r; rr = (rr < Nn) ? rr : (Nn - 1);
        xv[r] = *(const float4*)&x[(size_t)rr * 128 + kk * 4];
      }
#pragma unroll
      for (int j = 0; j < 4; ++j) {
        float2 w2 = *(const float2*)&Wl[(kk * 4 + j) * 128 + c0];
#pragma unroll
        for (int r = 0; r < 4; ++r) {
          float f = (&xv[r].x)[j];
          acc[r][0] = fmaf(f, w2.x, acc[r][0]);
          acc[r][1] = fmaf(f, w2.y, acc[r][1]);
        }
      }
    }
    for (int r = 0; r < nr; ++r) {
      const int row = row0 + r;
      __hip_bfloat162 hv;
      hv.x = __float2bfloat16(acc[r][0]);
      hv.y = __float2bfloat16(acc[r][1]);
      h2[(size_t)row * 64 + lane] = hv;
      float ps = acc[r][0] * as0 + acc[r][1] * as1;
      float pd = acc[r][0] * ad0 + acc[r][1] * ad1;
#pragma unroll
      for (int m = 1; m <= 16; m <<= 1) {
        ps += __shfl_xor(ps, m, 64);
        pd += __shfl_xor(pd, m, 64);
      }
      if (lane == 0)  { a_s[row * 2 + 0] = ps; a_d[row * 2 + 0] = pd; }
      if (lane == 32) { a_s[row * 2 + 1] = ps; a_d[row * 2 + 1] = pd; }
    }
  }
}

// per-chunk LDS histogram over buckets -> bhist[bucket][chunk]
__global__ __launch_bounds__(TH) void k_bhist(const int* __restrict__ dst,
                                              int* __restrict__ bhist, int E,
                                              int nbuck, int chunk) {
  __shared__ int hl[MAXBUCK];
  for (int i = threadIdx.x; i < nbuck; i += TH) hl[i] = 0;
  __syncthreads();
  const int s = blockIdx.x * chunk;
  const int e = (s + chunk < E) ? s + chunk : E;
  for (int i = s + threadIdx.x; i < e; i += TH)
    atomicAdd(&hl[dst[i] >> BSH], 1);
  __syncthreads();
  for (int b = threadIdx.x; b < nbuck; b += TH)
    bhist[b * NBLK + blockIdx.x] = hl[b];
}

// per bucket: exclusive scan over chunks -> raw cursors; write bucket total
__global__ __launch_bounds__(NBLK) void k_bscan(const int* __restrict__ bhist,
                                                int* __restrict__ cursors,
                                                int* __restrict__ totals,
                                                int nbuck) {
  __shared__ int tmp[NBLK];
  const int b = blockIdx.x;
  const int t = threadIdx.x;
  const int v = bhist[b * NBLK + t];
  tmp[t] = v;
  __syncthreads();
  for (int d = 1; d < NBLK; d <<= 1) {
    int add = (t >= d) ? tmp[t - d] : 0;
    __syncthreads();
    tmp[t] += add;
    __syncthreads();
  }
  cursors[t * nbuck + b] = tmp[t] - v;  // raw (no base)
  if (t == NBLK - 1) totals[b] = tmp[t];
}

// exclusive scan of bucket totals -> bases[0..nbuck]
__global__ __launch_bounds__(MAXBUCK) void k_bbase(const int* __restrict__ totals,
                                                   int* __restrict__ bases,
                                                   int nbuck) {
  __shared__ int tmp[MAXBUCK];
  const int t = threadIdx.x;
  const int v = (t < nbuck) ? totals[t] : 0;
  tmp[t] = v;
  __syncthreads();
  for (int d = 1; d < MAXBUCK; d <<= 1) {
    int add = (t >= d) ? tmp[t - d] : 0;
    __syncthreads();
    tmp[t] += add;
    __syncthreads();
  }
  if (t < nbuck) bases[t] = tmp[t] - v;
  if (t == nbuck - 1) bases[nbuck] = tmp[t];
}

// scatter packed (local_dst<<16 | src) into bucket-grouped pairs array
__global__ __launch_bounds__(TH) void k_binsert(
    const int* __restrict__ src, const int* __restrict__ dst,
    const int* __restrict__ cursors, const int* __restrict__ bases,
    int* __restrict__ pairs, int E, int nbuck, int chunk) {
  __shared__ int cur[MAXBUCK];
  for (int i = threadIdx.x; i < nbuck; i += TH)
    cur[i] = cursors[blockIdx.x * nbuck + i] + bases[i];
  __syncthreads();
  const int s = blockIdx.x * chunk;
  const int e = (s + chunk < E) ? s + chunk : E;
  for (int i = s + threadIdx.x; i < e; i += TH) {
    const int d = dst[i];
    const int b = d >> BSH;
    const int p = atomicAdd(&cur[b], 1);
    pairs[p] = ((d & (BSZ - 1)) << 16) | src[i];
  }
}

// per bucket: per-node counts + scan -> off/cnt, then LDS-atomic csr scatter
__global__ __launch_bounds__(256) void k_bucket(
    const int* __restrict__ pairs, const int* __restrict__ bases,
    int* __restrict__ off, int* __restrict__ cnt, int* __restrict__ csr,
    int Nn) {
  __shared__ int cl[BSZ];
  __shared__ int tmp[BSZ];
  __shared__ int cu[BSZ];
  const int b = blockIdx.x;
  const int t = threadIdx.x;
  const int n0 = b << BSH;
  if (t < BSZ) cl[t] = 0;
  __syncthreads();
  const int s = bases[b], e = bases[b + 1];
  for (int i = s + t; i < e; i += 256) atomicAdd(&cl[pairs[i] >> 16], 1);
  __syncthreads();
  int v = 0;
  if (t < BSZ) { v = cl[t]; tmp[t] = v; }
  __syncthreads();
  for (int d = 1; d < BSZ; d <<= 1) {
    int add = (t < BSZ && t >= d) ? tmp[t - d] : 0;
    __syncthreads();
    if (t < BSZ) tmp[t] += add;
    __syncthreads();
  }
  if (t < BSZ) {
    const int excl = tmp[t] - v;
    cu[t] = s + excl;
    const int node = n0 + t;
    if (node < Nn) { off[node] = s + excl; cnt[node] = v; }
  }
  __syncthreads();
  for (int i = s + t; i < e; i += 256) {
    const int pv = pairs[i];
    const int p = atomicAdd(&cu[pv >> 16], 1);
    csr[p] = pv & 0xffff;
  }
}

__device__ __forceinline__ float leaky02(float v) {
  return v > 0.f ? v : 0.2f * v;
}

// One wave per destination node.
__global__ __launch_bounds__(256) void k_aggr(
    const __hip_bfloat162* __restrict__ h2, const float* __restrict__ a_s,
    const float* __restrict__ a_d, const int* __restrict__ off,
    const int* __restrict__ cnt, const int* __restrict__ csr,
    const float* __restrict__ bias, float* __restrict__ out, int Nn) {
  const int wave = threadIdx.x >> 6;
  const int lane = threadIdx.x & 63;
  const int d = blockIdx.x * 4 + wave;
  if (d >= Nn) return;
  const int o = off[d];
  const int deg = cnt[d];
  const float ad0 = a_d[d * 2 + 0], ad1 = a_d[d * 2 + 1];
  const float NEG = -1e30f;
  float m0 = NEG, s0 = 0.f, m1 = NEG, s1 = 0.f;
  for (int e = lane; e < deg; e += 64) {
    int s = csr[o + e];
    float l0 = leaky02(a_s[s * 2 + 0] + ad0);
    float l1 = leaky02(a_s[s * 2 + 1] + ad1);
    float nm = fmaxf(m0, l0);
    s0 = s0 * __expf(m0 - nm) + __expf(l0 - nm); m0 = nm;
    nm = fmaxf(m1, l1);
    s1 = s1 * __expf(m1 - nm) + __expf(l1 - nm); m1 = nm;
  }
#pragma unroll
  for (int msk = 1; msk <= 32; msk <<= 1) {
    float om = __shfl_xor(m0, msk, 64), os = __shfl_xor(s0, msk, 64);
    float nm = fmaxf(m0, om);
    s0 = s0 * __expf(m0 - nm) + os * __expf(om - nm); m0 = nm;
    om = __shfl_xor(m1, msk, 64); os = __shfl_xor(s1, msk, 64);
    nm = fmaxf(m1, om);
    s1 = s1 * __expf(m1 - nm) + os * __expf(om - nm); m1 = nm;
  }
  {  // self loop
    float l0 = leaky02(a_s[d * 2 + 0] + ad0);
    float l1 = leaky02(a_s[d * 2 + 1] + ad1);
    float nm = fmaxf(m0, l0);
    s0 = s0 * __expf(m0 - nm) + __expf(l0 - nm); m0 = nm;
    nm = fmaxf(m1, l1);
    s1 = s1 * __expf(m1 - nm) + __expf(l1 - nm); m1 = nm;
  }
  const float msel = (lane < 32) ? m0 : m1;
  const float invsel = 1.f / (((lane < 32) ? s0 : s1) + 1e-16f);
  const float adsel = (lane < 32) ? ad0 : ad1;
  const int hsel = lane >> 5;
  float acc0 = 0.f, acc1 = 0.f;
  int e = 0;
  for (; e + 4 <= deg; e += 4) {
    int sA = csr[o + e + 0], sB = csr[o + e + 1];
    int sC = csr[o + e + 2], sD = csr[o + e + 3];
    __hip_bfloat162 hA = h2[(size_t)sA * 64 + lane];
    __hip_bfloat162 hB = h2[(size_t)sB * 64 + lane];
    __hip_bfloat162 hC = h2[(size_t)sC * 64 + lane];
    __hip_bfloat162 hD = h2[(size_t)sD * 64 + lane];
    float lgA = leaky02(a_s[sA * 2 + hsel] + adsel);
    float lgB = leaky02(a_s[sB * 2 + hsel] + adsel);
    float lgC = leaky02(a_s[sC * 2 + hsel] + adsel);
    float lgD = leaky02(a_s[sD * 2 + hsel] + adsel);
    float aA = __expf(lgA - msel) * invsel;
    float aB = __expf(lgB - msel) * invsel;
    float aC = __expf(lgC - msel) * invsel;
    float aD = __expf(lgD - msel) * invsel;
    acc0 = fmaf(aA, __bfloat162float(hA.x), acc0);
    acc1 = fmaf(aA, __bfloat162float(hA.y), acc1);
    acc0 = fmaf(aB, __bfloat162float(hB.x), acc0);
    acc1 = fmaf(aB, __bfloat162float(hB.y), acc1);
    acc0 = fmaf(aC, __bfloat162float(hC.x), acc0);
    acc1 = fmaf(aC, __bfloat162float(hC.y), acc1);
    acc0 = fmaf(aD, __bfloat162float(hD.x), acc0);
    acc1 = fmaf(aD, __bfloat162float(hD.y), acc1);
  }
  for (; e < deg; ++e) {
    int s = csr[o + e];
    float lg = leaky02(a_s[s * 2 + hsel] + adsel);
    float alpha = __expf(lg - msel) * invsel;
    __hip_bfloat162 hv = h2[(size_t)s * 64 + lane];
    acc0 = fmaf(alpha, __bfloat162float(hv.x), acc0);
    acc1 = fmaf(alpha, __bfloat162float(hv.y), acc1);
  }
  {  // self loop
    float lg = leaky02(a_s[d * 2 + hsel] + adsel);
    float alpha = __expf(lg - msel) * invsel;
    __hip_bfloat162 hv = h2[(size_t)d * 64 + lane];
    acc0 = fmaf(alpha, __bfloat162float(hv.x), acc0);
    acc1 = fmaf(alpha, __bfloat162float(hv.y), acc1);
  }
  float o0 = acc0 + __shfl_down(acc0, 32, 64);
  float o1 = acc1 + __shfl_down(acc1, 32, 64);
  if (lane < 32) {
    int c = lane * 2;
    float2 res = make_float2(0.5f * o0 + bias[c], 0.5f * o1 + bias[c + 1]);
    *(float2*)&out[(size_t)d * 64 + c] = res;
  }
}

extern "C" void kernel_launch(void* const* d_in, const int* in_sizes, int n_in,
                              void* d_out, int out_size, void* d_ws,
                              size_t ws_size, hipStream_t stream) {
  const float* x = (const float*)d_in[0];
  const float* W = (const float*)d_in[1];
  const float* att_s = (const float*)d_in[2];
  const float* att_d = (const float*)d_in[3];
  const float* bias = (const float*)d_in[4];
  const int* ei = (const int*)d_in[5];
  const int Nn = in_sizes[0] / 128;
  const int E = in_sizes[5] / 2;
  const int* src = ei;
  const int* dst = ei + E;
  float* out = (float*)d_out;

  const int nbuck = (Nn + BSZ - 1) >> BSH;          // 391 for N=50000
  const int chunk = (E + NBLK - 1) / NBLK;          // 6250 for E=1.6M

  // workspace layout
  __hip_bfloat162* h2 = (__hip_bfloat162*)d_ws;     // N*64 bf16x2 (12.8MB)
  float* a_s = (float*)(h2 + (size_t)Nn * 64);      // N*2
  float* a_d = a_s + (size_t)Nn * 2;                // N*2
  int* off = (int*)(a_d + (size_t)Nn * 2);          // N
  int* cnt = off + Nn;                              // N
  int* bhist = cnt + Nn;                            // nbuck*NBLK
  int* cursors = bhist + (size_t)nbuck * NBLK;      // NBLK*nbuck
  int* totals = cursors + (size_t)NBLK * nbuck;     // nbuck
  int* bases = totals + nbuck;                      // nbuck+1
  int* pairs = bases + nbuck + 1;                   // E
  int* csr = pairs + (size_t)E;                     // E

  hipLaunchKernelGGL(k_gemm, dim3(512), dim3(256), 0, stream, x, W, att_s,
                     att_d, h2, a_s, a_d, Nn);
  hipLaunchKernelGGL(k_bhist, dim3(NBLK), dim3(TH), 0, stream, dst, bhist, E,
                     nbuck, chunk);
  hipLaunchKernelGGL(k_bscan, dim3(nbuck), dim3(NBLK), 0, stream, bhist,
                     cursors, totals, nbuck);
  hipLaunchKernelGGL(k_bbase, dim3(1), dim3(MAXBUCK), 0, stream, totals, bases,
                     nbuck);
  hipLaunchKernelGGL(k_binsert, dim3(NBLK), dim3(TH), 0, stream, src, dst,
                     cursors, bases, pairs, E, nbuck, chunk);
  hipLaunchKernelGGL(k_bucket, dim3(nbuck), dim3(256), 0, stream, pairs, bases,
                     off, cnt, csr, Nn);
  hipLaunchKernelGGL(k_aggr, dim3((Nn + 3) / 4), dim3(256), 0, stream, h2, a_s,
                     a_d, off, cnt, csr, bias, out, Nn);
}

// Round 4
// 186.272 us; speedup vs baseline: 2.4807x; 1.0100x over previous
//
#include <hip/hip_runtime.h>
#include <hip/hip_bf16.h>

// ---------------------------------------------------------------------------
// GATConv (PyG-style, H=2 heads, C=64, concat=False -> head mean) on gfx950.
// Phases:
//   1. k_gemm   : h = x@W (fp32 math, W in LDS), h stored bf16; fused logits.
//   2. CSR build via two-level counting sort (no global atomics).
//   3. k_aggr   : per-dst wave: online softmax (pass A), then chunked pass B:
//                 each lane precomputes its edge's unnormalized exp-weight
//                 (1 expf / lane / 64 edges), inner loop = shfl-broadcast +
//                 bf16 h gather + fma. Normalization applied once at the end.
// ---------------------------------------------------------------------------

#define NBLK 256   // edge chunks (= threads in k_bscan)
#define TH 512     // threads for bhist/binsert
#define BSH 7      // bucket = dst >> 7
#define BSZ 128    // nodes per bucket
#define MAXBUCK 512

// h = x @ W  (x: [N,128], W: [128,128]) -> bf16 h, plus fp32 a_s[n][h], a_d[n][h]
__global__ __launch_bounds__(256) void k_gemm(
    const float* __restrict__ x, const float* __restrict__ W,
    const float* __restrict__ att_s, const float* __restrict__ att_d,
    __hip_bfloat162* __restrict__ h2, float* __restrict__ a_s,
    float* __restrict__ a_d, int Nn) {
  __shared__ float Wl[128 * 128];  // 64 KB
  {
    const float4* W4 = (const float4*)W;
    float4* Wl4 = (float4*)Wl;
    for (int i = threadIdx.x; i < 4096; i += 256) Wl4[i] = W4[i];
  }
  __syncthreads();
  const int wave = threadIdx.x >> 6;
  const int lane = threadIdx.x & 63;
  const int c0 = lane * 2;
  const float as0 = att_s[c0], as1 = att_s[c0 + 1];
  const float ad0 = att_d[c0], ad1 = att_d[c0 + 1];
  const int ngroups = (Nn + 3) >> 2;
  for (int g = blockIdx.x * 4 + wave; g < ngroups; g += gridDim.x * 4) {
    const int row0 = g * 4;
    const int nr = (Nn - row0 < 4) ? (Nn - row0) : 4;
    float acc[4][2];
#pragma unroll
    for (int r = 0; r < 4; ++r) { acc[r][0] = 0.f; acc[r][1] = 0.f; }
    for (int kk = 0; kk < 32; ++kk) {
      float4 xv[4];
#pragma unroll
      for (int r = 0; r < 4; ++r) {
        int rr = row0 + r; rr = (rr < Nn) ? rr : (Nn - 1);
        xv[r] = *(const float4*)&x[(size_t)rr * 128 + kk * 4];
      }
#pragma unroll
      for (int j = 0; j < 4; ++j) {
        float2 w2 = *(const float2*)&Wl[(kk * 4 + j) * 128 + c0];
#pragma unroll
        for (int r = 0; r < 4; ++r) {
          float f = (&xv[r].x)[j];
          acc[r][0] = fmaf(f, w2.x, acc[r][0]);
          acc[r][1] = fmaf(f, w2.y, acc[r][1]);
        }
      }
    }
    for (int r = 0; r < nr; ++r) {
      const int row = row0 + r;
      __hip_bfloat162 hv;
      hv.x = __float2bfloat16(acc[r][0]);
      hv.y = __float2bfloat16(acc[r][1]);
      h2[(size_t)row * 64 + lane] = hv;
      float ps = acc[r][0] * as0 + acc[r][1] * as1;
      float pd = acc[r][0] * ad0 + acc[r][1] * ad1;
#pragma unroll
      for (int m = 1; m <= 16; m <<= 1) {
        ps += __shfl_xor(ps, m, 64);
        pd += __shfl_xor(pd, m, 64);
      }
      if (lane == 0)  { a_s[row * 2 + 0] = ps; a_d[row * 2 + 0] = pd; }
      if (lane == 32) { a_s[row * 2 + 1] = ps; a_d[row * 2 + 1] = pd; }
    }
  }
}

// per-chunk LDS histogram over buckets -> bhist[bucket][chunk]
__global__ __launch_bounds__(TH) void k_bhist(const int* __restrict__ dst,
                                              int* __restrict__ bhist, int E,
                                              int nbuck, int chunk) {
  __shared__ int hl[MAXBUCK];
  for (int i = threadIdx.x; i < nbuck; i += TH) hl[i] = 0;
  __syncthreads();
  const int s = blockIdx.x * chunk;
  const int e = (s + chunk < E) ? s + chunk : E;
  for (int i = s + threadIdx.x; i < e; i += TH)
    atomicAdd(&hl[dst[i] >> BSH], 1);
  __syncthreads();
  for (int b = threadIdx.x; b < nbuck; b += TH)
    bhist[b * NBLK + blockIdx.x] = hl[b];
}

// per bucket: exclusive scan over chunks -> raw cursors; write bucket total
__global__ __launch_bounds__(NBLK) void k_bscan(const int* __restrict__ bhist,
                                                int* __restrict__ cursors,
                                                int* __restrict__ totals,
                                                int nbuck) {
  __shared__ int tmp[NBLK];
  const int b = blockIdx.x;
  const int t = threadIdx.x;
  const int v = bhist[b * NBLK + t];
  tmp[t] = v;
  __syncthreads();
  for (int d = 1; d < NBLK; d <<= 1) {
    int add = (t >= d) ? tmp[t - d] : 0;
    __syncthreads();
    tmp[t] += add;
    __syncthreads();
  }
  cursors[t * nbuck + b] = tmp[t] - v;  // raw (no base)
  if (t == NBLK - 1) totals[b] = tmp[t];
}

// exclusive scan of bucket totals -> bases[0..nbuck]
__global__ __launch_bounds__(MAXBUCK) void k_bbase(const int* __restrict__ totals,
                                                   int* __restrict__ bases,
                                                   int nbuck) {
  __shared__ int tmp[MAXBUCK];
  const int t = threadIdx.x;
  const int v = (t < nbuck) ? totals[t] : 0;
  tmp[t] = v;
  __syncthreads();
  for (int d = 1; d < MAXBUCK; d <<= 1) {
    int add = (t >= d) ? tmp[t - d] : 0;
    __syncthreads();
    tmp[t] += add;
    __syncthreads();
  }
  if (t < nbuck) bases[t] = tmp[t] - v;
  if (t == nbuck - 1) bases[nbuck] = tmp[t];
}

// scatter packed (local_dst<<16 | src) into bucket-grouped pairs array
__global__ __launch_bounds__(TH) void k_binsert(
    const int* __restrict__ src, const int* __restrict__ dst,
    const int* __restrict__ cursors, const int* __restrict__ bases,
    int* __restrict__ pairs, int E, int nbuck, int chunk) {
  __shared__ int cur[MAXBUCK];
  for (int i = threadIdx.x; i < nbuck; i += TH)
    cur[i] = cursors[blockIdx.x * nbuck + i] + bases[i];
  __syncthreads();
  const int s = blockIdx.x * chunk;
  const int e = (s + chunk < E) ? s + chunk : E;
  for (int i = s + threadIdx.x; i < e; i += TH) {
    const int d = dst[i];
    const int b = d >> BSH;
    const int p = atomicAdd(&cur[b], 1);
    pairs[p] = ((d & (BSZ - 1)) << 16) | src[i];
  }
}

// per bucket: per-node counts + scan -> off/cnt, then LDS-atomic csr scatter
__global__ __launch_bounds__(256) void k_bucket(
    const int* __restrict__ pairs, const int* __restrict__ bases,
    int* __restrict__ off, int* __restrict__ cnt, int* __restrict__ csr,
    int Nn) {
  __shared__ int cl[BSZ];
  __shared__ int tmp[BSZ];
  __shared__ int cu[BSZ];
  const int b = blockIdx.x;
  const int t = threadIdx.x;
  const int n0 = b << BSH;
  if (t < BSZ) cl[t] = 0;
  __syncthreads();
  const int s = bases[b], e = bases[b + 1];
  for (int i = s + t; i < e; i += 256) atomicAdd(&cl[pairs[i] >> 16], 1);
  __syncthreads();
  int v = 0;
  if (t < BSZ) { v = cl[t]; tmp[t] = v; }
  __syncthreads();
  for (int d = 1; d < BSZ; d <<= 1) {
    int add = (t < BSZ && t >= d) ? tmp[t - d] : 0;
    __syncthreads();
    if (t < BSZ) tmp[t] += add;
    __syncthreads();
  }
  if (t < BSZ) {
    const int excl = tmp[t] - v;
    cu[t] = s + excl;
    const int node = n0 + t;
    if (node < Nn) { off[node] = s + excl; cnt[node] = v; }
  }
  __syncthreads();
  for (int i = s + t; i < e; i += 256) {
    const int pv = pairs[i];
    const int p = atomicAdd(&cu[pv >> 16], 1);
    csr[p] = pv & 0xffff;
  }
}

__device__ __forceinline__ float leaky02(float v) {
  return v > 0.f ? v : 0.2f * v;
}

// One wave per destination node.
__global__ __launch_bounds__(256) void k_aggr(
    const __hip_bfloat162* __restrict__ h2, const float* __restrict__ a_s,
    const float* __restrict__ a_d, const int* __restrict__ off,
    const int* __restrict__ cnt, const int* __restrict__ csr,
    const float* __restrict__ bias, float* __restrict__ out, int Nn) {
  const int wave = threadIdx.x >> 6;
  const int lane = threadIdx.x & 63;
  const int d = blockIdx.x * 4 + wave;
  if (d >= Nn) return;
  const int o = off[d];
  const int deg = cnt[d];
  const float2 ad2 = *(const float2*)&a_d[d * 2];
  const float NEG = -1e30f;
  float m0 = NEG, s0 = 0.f, m1 = NEG, s1 = 0.f;
  // Pass A: lane-parallel online max/sum of exp(leaky(logit)) per head
  for (int e = lane; e < deg; e += 64) {
    int s = csr[o + e];
    float2 as2 = *(const float2*)&a_s[s * 2];
    float l0 = leaky02(as2.x + ad2.x);
    float l1 = leaky02(as2.y + ad2.y);
    float nm = fmaxf(m0, l0);
    s0 = s0 * __expf(m0 - nm) + __expf(l0 - nm); m0 = nm;
    nm = fmaxf(m1, l1);
    s1 = s1 * __expf(m1 - nm) + __expf(l1 - nm); m1 = nm;
  }
#pragma unroll
  for (int msk = 1; msk <= 32; msk <<= 1) {
    float om = __shfl_xor(m0, msk, 64), os = __shfl_xor(s0, msk, 64);
    float nm = fmaxf(m0, om);
    s0 = s0 * __expf(m0 - nm) + os * __expf(om - nm); m0 = nm;
    om = __shfl_xor(m1, msk, 64); os = __shfl_xor(s1, msk, 64);
    nm = fmaxf(m1, om);
    s1 = s1 * __expf(m1 - nm) + os * __expf(om - nm); m1 = nm;
  }
  {  // self loop
    float2 as2 = *(const float2*)&a_s[d * 2];
    float l0 = leaky02(as2.x + ad2.x);
    float l1 = leaky02(as2.y + ad2.y);
    float nm = fmaxf(m0, l0);
    s0 = s0 * __expf(m0 - nm) + __expf(l0 - nm); m0 = nm;
    nm = fmaxf(m1, l1);
    s1 = s1 * __expf(m1 - nm) + __expf(l1 - nm); m1 = nm;
  }
  // Pass B: chunked. Each lane precomputes its edge's UNNORMALIZED weight
  // (exp(l - m)); inner loop broadcasts via shfl and gathers h. Normalize once
  // at the end (acc *= 1/esum).
  float acc0 = 0.f, acc1 = 0.f;
  for (int c = 0; c < deg; c += 64) {
    int rem = deg - c; if (rem > 64) rem = 64;
    int sl = 0; float al0 = 0.f, al1 = 0.f;
    if (lane < rem) {
      sl = csr[o + c + lane];
      float2 as2 = *(const float2*)&a_s[sl * 2];
      al0 = __expf(leaky02(as2.x + ad2.x) - m0);
      al1 = __expf(leaky02(as2.y + ad2.y) - m1);
    }
    int j = 0;
    for (; j + 2 <= rem; j += 2) {
      int sA = __shfl(sl, j, 64);
      int sB = __shfl(sl, j + 1, 64);
      float a0A = __shfl(al0, j, 64), a1A = __shfl(al1, j, 64);
      float a0B = __shfl(al0, j + 1, 64), a1B = __shfl(al1, j + 1, 64);
      float avA = (lane < 32) ? a0A : a1A;
      float avB = (lane < 32) ? a0B : a1B;
      __hip_bfloat162 hA = h2[(size_t)sA * 64 + lane];
      __hip_bfloat162 hB = h2[(size_t)sB * 64 + lane];
      acc0 = fmaf(avA, __bfloat162float(hA.x), acc0);
      acc1 = fmaf(avA, __bfloat162float(hA.y), acc1);
      acc0 = fmaf(avB, __bfloat162float(hB.x), acc0);
      acc1 = fmaf(avB, __bfloat162float(hB.y), acc1);
    }
    for (; j < rem; ++j) {
      int s = __shfl(sl, j, 64);
      float a0 = __shfl(al0, j, 64), a1 = __shfl(al1, j, 64);
      float av = (lane < 32) ? a0 : a1;
      __hip_bfloat162 hv = h2[(size_t)s * 64 + lane];
      acc0 = fmaf(av, __bfloat162float(hv.x), acc0);
      acc1 = fmaf(av, __bfloat162float(hv.y), acc1);
    }
  }
  {  // self loop (unnormalized)
    float2 as2 = *(const float2*)&a_s[d * 2];
    float av = (lane < 32) ? __expf(leaky02(as2.x + ad2.x) - m0)
                           : __expf(leaky02(as2.y + ad2.y) - m1);
    __hip_bfloat162 hv = h2[(size_t)d * 64 + lane];
    acc0 = fmaf(av, __bfloat162float(hv.x), acc0);
    acc1 = fmaf(av, __bfloat162float(hv.y), acc1);
  }
  const float invsel = 1.f / (((lane < 32) ? s0 : s1) + 1e-16f);
  acc0 *= invsel; acc1 *= invsel;
  // head mean: lane l (<32, head0 ch 2l,2l+1) + lane l+32 (head1 ch 2l,2l+1)
  float o0 = acc0 + __shfl_down(acc0, 32, 64);
  float o1 = acc1 + __shfl_down(acc1, 32, 64);
  if (lane < 32) {
    int c = lane * 2;
    float2 res = make_float2(0.5f * o0 + bias[c], 0.5f * o1 + bias[c + 1]);
    *(float2*)&out[(size_t)d * 64 + c] = res;
  }
}

extern "C" void kernel_launch(void* const* d_in, const int* in_sizes, int n_in,
                              void* d_out, int out_size, void* d_ws,
                              size_t ws_size, hipStream_t stream) {
  const float* x = (const float*)d_in[0];
  const float* W = (const float*)d_in[1];
  const float* att_s = (const float*)d_in[2];
  const float* att_d = (const float*)d_in[3];
  const float* bias = (const float*)d_in[4];
  const int* ei = (const int*)d_in[5];
  const int Nn = in_sizes[0] / 128;
  const int E = in_sizes[5] / 2;
  const int* src = ei;
  const int* dst = ei + E;
  float* out = (float*)d_out;

  const int nbuck = (Nn + BSZ - 1) >> BSH;          // 391 for N=50000
  const int chunk = (E + NBLK - 1) / NBLK;          // 6250 for E=1.6M

  // workspace layout
  __hip_bfloat162* h2 = (__hip_bfloat162*)d_ws;     // N*64 bf16x2 (12.8MB)
  float* a_s = (float*)(h2 + (size_t)Nn * 64);      // N*2
  float* a_d = a_s + (size_t)Nn * 2;                // N*2
  int* off = (int*)(a_d + (size_t)Nn * 2);          // N
  int* cnt = off + Nn;                              // N
  int* bhist = cnt + Nn;                            // nbuck*NBLK
  int* cursors = bhist + (size_t)nbuck * NBLK;      // NBLK*nbuck
  int* totals = cursors + (size_t)NBLK * nbuck;     // nbuck
  int* bases = totals + nbuck;                      // nbuck+1
  int* pairs = bases + nbuck + 1;                   // E
  int* csr = pairs + (size_t)E;                     // E

  hipLaunchKernelGGL(k_gemm, dim3(512), dim3(256), 0, stream, x, W, att_s,
                     att_d, h2, a_s, a_d, Nn);
  hipLaunchKernelGGL(k_bhist, dim3(NBLK), dim3(TH), 0, stream, dst, bhist, E,
                     nbuck, chunk);
  hipLaunchKernelGGL(k_bscan, dim3(nbuck), dim3(NBLK), 0, stream, bhist,
                     cursors, totals, nbuck);
  hipLaunchKernelGGL(k_bbase, dim3(1), dim3(MAXBUCK), 0, stream, totals, bases,
                     nbuck);
  hipLaunchKernelGGL(k_binsert, dim3(NBLK), dim3(TH), 0, stream, src, dst,
                     cursors, bases, pairs, E, nbuck, chunk);
  hipLaunchKernelGGL(k_bucket, dim3(nbuck), dim3(256), 0, stream, pairs, bases,
                     off, cnt, csr, Nn);
  hipLaunchKernelGGL(k_aggr, dim3((Nn + 3) / 4), dim3(256), 0, stream, h2, a_s,
                     a_d, off, cnt, csr, bias, out, Nn);
}

// Round 5
// 164.946 us; speedup vs baseline: 2.8014x; 1.1293x over previous
//
#include <hip/hip_runtime.h>
#include <hip/hip_bf16.h>

// ---------------------------------------------------------------------------
// GATConv (PyG-style, H=2 heads, C=64, concat=False -> head mean) on gfx950.
// Phases:
//   1. k_gemm   : h = x@W (fp32 math, W in LDS), h stored bf16; fused logits.
//   2. CSR build via two-level counting sort (no global atomics).
//   3. k_aggr   : per-dst wave, MAX-FREE softmax (exp(e)/sum exp(e) ==
//                 exp(e-m)/sum exp(e-m) exactly; |e|<~10 so fp32 safe).
//                 Single pass over edges: each lane precomputes its edge's
//                 {voff, w0, w1} into a per-wave LDS array (ds_write_b128),
//                 inner loop does ONE uniform ds_read_b128 broadcast per edge
//                 (replaces 3 ds_bpermute), gathers bf16 h row, 2 fma.
//                 esum accumulated per-lane, one butterfly reduce per node,
//                 normalization applied once at the end.
// ---------------------------------------------------------------------------

#define NBLK 256   // edge chunks (= threads in k_bscan)
#define TH 512     // threads for bhist/binsert
#define BSH 7      // bucket = dst >> 7
#define BSZ 128    // nodes per bucket
#define MAXBUCK 512

// h = x @ W  (x: [N,128], W: [128,128]) -> bf16 h, plus fp32 a_s[n][h], a_d[n][h]
__global__ __launch_bounds__(256) void k_gemm(
    const float* __restrict__ x, const float* __restrict__ W,
    const float* __restrict__ att_s, const float* __restrict__ att_d,
    __hip_bfloat162* __restrict__ h2, float* __restrict__ a_s,
    float* __restrict__ a_d, int Nn) {
  __shared__ float Wl[128 * 128];  // 64 KB
  {
    const float4* W4 = (const float4*)W;
    float4* Wl4 = (float4*)Wl;
    for (int i = threadIdx.x; i < 4096; i += 256) Wl4[i] = W4[i];
  }
  __syncthreads();
  const int wave = threadIdx.x >> 6;
  const int lane = threadIdx.x & 63;
  const int c0 = lane * 2;
  const float as0 = att_s[c0], as1 = att_s[c0 + 1];
  const float ad0 = att_d[c0], ad1 = att_d[c0 + 1];
  const int ngroups = (Nn + 3) >> 2;
  for (int g = blockIdx.x * 4 + wave; g < ngroups; g += gridDim.x * 4) {
    const int row0 = g * 4;
    const int nr = (Nn - row0 < 4) ? (Nn - row0) : 4;
    float acc[4][2];
#pragma unroll
    for (int r = 0; r < 4; ++r) { acc[r][0] = 0.f; acc[r][1] = 0.f; }
    for (int kk = 0; kk < 32; ++kk) {
      float4 xv[4];
#pragma unroll
      for (int r = 0; r < 4; ++r) {
        int rr = row0 + r; rr = (rr < Nn) ? rr : (Nn - 1);
        xv[r] = *(const float4*)&x[(size_t)rr * 128 + kk * 4];
      }
#pragma unroll
      for (int j = 0; j < 4; ++j) {
        float2 w2 = *(const float2*)&Wl[(kk * 4 + j) * 128 + c0];
#pragma unroll
        for (int r = 0; r < 4; ++r) {
          float f = (&xv[r].x)[j];
          acc[r][0] = fmaf(f, w2.x, acc[r][0]);
          acc[r][1] = fmaf(f, w2.y, acc[r][1]);
        }
      }
    }
    for (int r = 0; r < nr; ++r) {
      const int row = row0 + r;
      __hip_bfloat162 hv;
      hv.x = __float2bfloat16(acc[r][0]);
      hv.y = __float2bfloat16(acc[r][1]);
      h2[(size_t)row * 64 + lane] = hv;
      float ps = acc[r][0] * as0 + acc[r][1] * as1;
      float pd = acc[r][0] * ad0 + acc[r][1] * ad1;
#pragma unroll
      for (int m = 1; m <= 16; m <<= 1) {
        ps += __shfl_xor(ps, m, 64);
        pd += __shfl_xor(pd, m, 64);
      }
      if (lane == 0)  { a_s[row * 2 + 0] = ps; a_d[row * 2 + 0] = pd; }
      if (lane == 32) { a_s[row * 2 + 1] = ps; a_d[row * 2 + 1] = pd; }
    }
  }
}

// per-chunk LDS histogram over buckets -> bhist[bucket][chunk]
__global__ __launch_bounds__(TH) void k_bhist(const int* __restrict__ dst,
                                              int* __restrict__ bhist, int E,
                                              int nbuck, int chunk) {
  __shared__ int hl[MAXBUCK];
  for (int i = threadIdx.x; i < nbuck; i += TH) hl[i] = 0;
  __syncthreads();
  const int s = blockIdx.x * chunk;
  const int e = (s + chunk < E) ? s + chunk : E;
  for (int i = s + threadIdx.x; i < e; i += TH)
    atomicAdd(&hl[dst[i] >> BSH], 1);
  __syncthreads();
  for (int b = threadIdx.x; b < nbuck; b += TH)
    bhist[b * NBLK + blockIdx.x] = hl[b];
}

// per bucket: exclusive scan over chunks -> raw cursors; write bucket total
__global__ __launch_bounds__(NBLK) void k_bscan(const int* __restrict__ bhist,
                                                int* __restrict__ cursors,
                                                int* __restrict__ totals,
                                                int nbuck) {
  __shared__ int tmp[NBLK];
  const int b = blockIdx.x;
  const int t = threadIdx.x;
  const int v = bhist[b * NBLK + t];
  tmp[t] = v;
  __syncthreads();
  for (int d = 1; d < NBLK; d <<= 1) {
    int add = (t >= d) ? tmp[t - d] : 0;
    __syncthreads();
    tmp[t] += add;
    __syncthreads();
  }
  cursors[t * nbuck + b] = tmp[t] - v;  // raw (no base)
  if (t == NBLK - 1) totals[b] = tmp[t];
}

// exclusive scan of bucket totals -> bases[0..nbuck]
__global__ __launch_bounds__(MAXBUCK) void k_bbase(const int* __restrict__ totals,
                                                   int* __restrict__ bases,
                                                   int nbuck) {
  __shared__ int tmp[MAXBUCK];
  const int t = threadIdx.x;
  const int v = (t < nbuck) ? totals[t] : 0;
  tmp[t] = v;
  __syncthreads();
  for (int d = 1; d < MAXBUCK; d <<= 1) {
    int add = (t >= d) ? tmp[t - d] : 0;
    __syncthreads();
    tmp[t] += add;
    __syncthreads();
  }
  if (t < nbuck) bases[t] = tmp[t] - v;
  if (t == nbuck - 1) bases[nbuck] = tmp[t];
}

// scatter packed (local_dst<<16 | src) into bucket-grouped pairs array
__global__ __launch_bounds__(TH) void k_binsert(
    const int* __restrict__ src, const int* __restrict__ dst,
    const int* __restrict__ cursors, const int* __restrict__ bases,
    int* __restrict__ pairs, int E, int nbuck, int chunk) {
  __shared__ int cur[MAXBUCK];
  for (int i = threadIdx.x; i < nbuck; i += TH)
    cur[i] = cursors[blockIdx.x * nbuck + i] + bases[i];
  __syncthreads();
  const int s = blockIdx.x * chunk;
  const int e = (s + chunk < E) ? s + chunk : E;
  for (int i = s + threadIdx.x; i < e; i += TH) {
    const int d = dst[i];
    const int b = d >> BSH;
    const int p = atomicAdd(&cur[b], 1);
    pairs[p] = ((d & (BSZ - 1)) << 16) | src[i];
  }
}

// per bucket: per-node counts + scan -> off/cnt, then LDS-atomic csr scatter
__global__ __launch_bounds__(256) void k_bucket(
    const int* __restrict__ pairs, const int* __restrict__ bases,
    int* __restrict__ off, int* __restrict__ cnt, int* __restrict__ csr,
    int Nn) {
  __shared__ int cl[BSZ];
  __shared__ int tmp[BSZ];
  __shared__ int cu[BSZ];
  const int b = blockIdx.x;
  const int t = threadIdx.x;
  const int n0 = b << BSH;
  if (t < BSZ) cl[t] = 0;
  __syncthreads();
  const int s = bases[b], e = bases[b + 1];
  for (int i = s + t; i < e; i += 256) atomicAdd(&cl[pairs[i] >> 16], 1);
  __syncthreads();
  int v = 0;
  if (t < BSZ) { v = cl[t]; tmp[t] = v; }
  __syncthreads();
  for (int d = 1; d < BSZ; d <<= 1) {
    int add = (t < BSZ && t >= d) ? tmp[t - d] : 0;
    __syncthreads();
    if (t < BSZ) tmp[t] += add;
    __syncthreads();
  }
  if (t < BSZ) {
    const int excl = tmp[t] - v;
    cu[t] = s + excl;
    const int node = n0 + t;
    if (node < Nn) { off[node] = s + excl; cnt[node] = v; }
  }
  __syncthreads();
  for (int i = s + t; i < e; i += 256) {
    const int pv = pairs[i];
    const int p = atomicAdd(&cu[pv >> 16], 1);
    csr[p] = pv & 0xffff;
  }
}

__device__ __forceinline__ float leaky02(float v) {
  return fmaxf(v, 0.2f * v);  // slope 0.2 leaky relu (valid for both signs)
}

// One wave per destination node. Max-free softmax, single edge sweep.
__global__ __launch_bounds__(256) void k_aggr(
    const __hip_bfloat162* __restrict__ h2, const float* __restrict__ a_s,
    const float* __restrict__ a_d, const int* __restrict__ off,
    const int* __restrict__ cnt, const int* __restrict__ csr,
    const float* __restrict__ bias, float* __restrict__ out, int Nn) {
  // per-wave staging: 64 edge entries of {byte_voff, w0, w1, pad}
  __shared__ uint4 ew[4][64];
  const int wave = threadIdx.x >> 6;
  const int lane = threadIdx.x & 63;
  const int d = blockIdx.x * 4 + wave;
  if (d >= Nn) return;
  const int o = off[d];
  const int deg = cnt[d];
  const float2 ad2 = *(const float2*)&a_d[d * 2];
  const char* hb = (const char*)h2;
  const unsigned l4 = lane * 4u;

  float acc0 = 0.f, acc1 = 0.f;   // this lane's 2 channels
  float sw0 = 0.f, sw1 = 0.f;     // per-lane partial esum (head0, head1)

  for (int c = 0; c < deg; c += 64) {
    int rem = deg - c; if (rem > 64) rem = 64;
    {
      unsigned voff = 0; float w0 = 0.f, w1 = 0.f;
      if (lane < rem) {
        int sl = csr[o + c + lane];
        float2 as2 = *(const float2*)&a_s[sl * 2];
        w0 = __expf(leaky02(as2.x + ad2.x));
        w1 = __expf(leaky02(as2.y + ad2.y));
        voff = (unsigned)sl << 8;  // byte offset of h2 row (256 B/row)
        sw0 += w0; sw1 += w1;
      }
      uint4 t;
      t.x = voff;
      t.y = __float_as_uint(w0);
      t.z = __float_as_uint(w1);
      t.w = 0;
      ew[wave][lane] = t;  // ds_write_b128; same-wave consumer, lgkmcnt order
    }
    int j = 0;
    for (; j + 4 <= rem; j += 4) {
      uint4 tA = ew[wave][j + 0];
      uint4 tB = ew[wave][j + 1];
      uint4 tC = ew[wave][j + 2];
      uint4 tD = ew[wave][j + 3];
      float avA = __uint_as_float((lane < 32) ? tA.y : tA.z);
      float avB = __uint_as_float((lane < 32) ? tB.y : tB.z);
      float avC = __uint_as_float((lane < 32) ? tC.y : tC.z);
      float avD = __uint_as_float((lane < 32) ? tD.y : tD.z);
      __hip_bfloat162 hA = *(const __hip_bfloat162*)(hb + (size_t)(tA.x + l4));
      __hip_bfloat162 hB = *(const __hip_bfloat162*)(hb + (size_t)(tB.x + l4));
      __hip_bfloat162 hC = *(const __hip_bfloat162*)(hb + (size_t)(tC.x + l4));
      __hip_bfloat162 hD = *(const __hip_bfloat162*)(hb + (size_t)(tD.x + l4));
      acc0 = fmaf(avA, __bfloat162float(hA.x), acc0);
      acc1 = fmaf(avA, __bfloat162float(hA.y), acc1);
      acc0 = fmaf(avB, __bfloat162float(hB.x), acc0);
      acc1 = fmaf(avB, __bfloat162float(hB.y), acc1);
      acc0 = fmaf(avC, __bfloat162float(hC.x), acc0);
      acc1 = fmaf(avC, __bfloat162float(hC.y), acc1);
      acc0 = fmaf(avD, __bfloat162float(hD.x), acc0);
      acc1 = fmaf(avD, __bfloat162float(hD.y), acc1);
    }
    for (; j < rem; ++j) {
      uint4 t = ew[wave][j];
      float av = __uint_as_float((lane < 32) ? t.y : t.z);
      __hip_bfloat162 hv = *(const __hip_bfloat162*)(hb + (size_t)(t.x + l4));
      acc0 = fmaf(av, __bfloat162float(hv.x), acc0);
      acc1 = fmaf(av, __bfloat162float(hv.y), acc1);
    }
  }
  // butterfly-reduce per-lane esum partials across the wave
#pragma unroll
  for (int msk = 1; msk <= 32; msk <<= 1) {
    sw0 += __shfl_xor(sw0, msk, 64);
    sw1 += __shfl_xor(sw1, msk, 64);
  }
  // self loop (weight computed uniformly on all lanes)
  {
    float2 as2 = *(const float2*)&a_s[d * 2];
    float w0 = __expf(leaky02(as2.x + ad2.x));
    float w1 = __expf(leaky02(as2.y + ad2.y));
    sw0 += w0; sw1 += w1;
    float av = (lane < 32) ? w0 : w1;
    __hip_bfloat162 hv = h2[(size_t)d * 64 + lane];
    acc0 = fmaf(av, __bfloat162float(hv.x), acc0);
    acc1 = fmaf(av, __bfloat162float(hv.y), acc1);
  }
  const float invsel = 1.f / (((lane < 32) ? sw0 : sw1) + 1e-16f);
  acc0 *= invsel; acc1 *= invsel;
  // head mean: lane l (<32, head0 ch 2l,2l+1) + lane l+32 (head1 ch 2l,2l+1)
  float o0 = acc0 + __shfl_down(acc0, 32, 64);
  float o1 = acc1 + __shfl_down(acc1, 32, 64);
  if (lane < 32) {
    int c = lane * 2;
    float2 res = make_float2(0.5f * o0 + bias[c], 0.5f * o1 + bias[c + 1]);
    *(float2*)&out[(size_t)d * 64 + c] = res;
  }
}

extern "C" void kernel_launch(void* const* d_in, const int* in_sizes, int n_in,
                              void* d_out, int out_size, void* d_ws,
                              size_t ws_size, hipStream_t stream) {
  const float* x = (const float*)d_in[0];
  const float* W = (const float*)d_in[1];
  const float* att_s = (const float*)d_in[2];
  const float* att_d = (const float*)d_in[3];
  const float* bias = (const float*)d_in[4];
  const int* ei = (const int*)d_in[5];
  const int Nn = in_sizes[0] / 128;
  const int E = in_sizes[5] / 2;
  const int* src = ei;
  const int* dst = ei + E;
  float* out = (float*)d_out;

  const int nbuck = (Nn + BSZ - 1) >> BSH;          // 391 for N=50000
  const int chunk = (E + NBLK - 1) / NBLK;          // 6250 for E=1.6M

  // workspace layout
  __hip_bfloat162* h2 = (__hip_bfloat162*)d_ws;     // N*64 bf16x2 (12.8MB)
  float* a_s = (float*)(h2 + (size_t)Nn * 64);      // N*2
  float* a_d = a_s + (size_t)Nn * 2;                // N*2
  int* off = (int*)(a_d + (size_t)Nn * 2);          // N
  int* cnt = off + Nn;                              // N
  int* bhist = cnt + Nn;                            // nbuck*NBLK
  int* cursors = bhist + (size_t)nbuck * NBLK;      // NBLK*nbuck
  int* totals = cursors + (size_t)NBLK * nbuck;     // nbuck
  int* bases = totals + nbuck;                      // nbuck+1
  int* pairs = bases + nbuck + 1;                   // E
  int* csr = pairs + (size_t)E;                     // E

  hipLaunchKernelGGL(k_gemm, dim3(512), dim3(256), 0, stream, x, W, att_s,
                     att_d, h2, a_s, a_d, Nn);
  hipLaunchKernelGGL(k_bhist, dim3(NBLK), dim3(TH), 0, stream, dst, bhist, E,
                     nbuck, chunk);
  hipLaunchKernelGGL(k_bscan, dim3(nbuck), dim3(NBLK), 0, stream, bhist,
                     cursors, totals, nbuck);
  hipLaunchKernelGGL(k_bbase, dim3(1), dim3(MAXBUCK), 0, stream, totals, bases,
                     nbuck);
  hipLaunchKernelGGL(k_binsert, dim3(NBLK), dim3(TH), 0, stream, src, dst,
                     cursors, bases, pairs, E, nbuck, chunk);
  hipLaunchKernelGGL(k_bucket, dim3(nbuck), dim3(256), 0, stream, pairs, bases,
                     off, cnt, csr, Nn);
  hipLaunchKernelGGL(k_aggr, dim3((Nn + 3) / 4), dim3(256), 0, stream, h2, a_s,
                     a_d, off, cnt, csr, bias, out, Nn);
}

// Round 6
// 123.236 us; speedup vs baseline: 3.7496x; 1.3385x over previous
//
#include <hip/hip_runtime.h>
#include <hip/hip_bf16.h>

// ---------------------------------------------------------------------------
// GATConv (PyG-style, H=2 heads, C=64, concat=False -> head mean) on gfx950.
// Phases:
//   0. k_wa     : WA[k][4] = W @ {att_s,att_d per head}  (logits = x @ WA)
//   1. k_gemm   : h = x@W via bf16 MFMA 16x16x32. 64-row tile, x->bf16 LDS
//                 (XOR-swizzled), W-frags in registers; wave 3 contracts an
//                 extra WA fragment -> a_s/a_d directly from MFMA acc.
//   2. CSR build via two-level counting sort (no global atomics).
//   3. k_aggr   : per-dst wave, max-free softmax, single edge sweep; uniform
//                 ds_read_b128 broadcast of {voff,w0,w1}; bf16 h gather.
// ---------------------------------------------------------------------------

#define NBLK 256   // edge chunks (= threads in k_bscan)
#define TH 512     // threads for bhist/binsert
#define BSH 7      // bucket = dst >> 7
#define BSZ 128    // nodes per bucket
#define MAXBUCK 512

typedef __attribute__((ext_vector_type(8))) short bf16x8;
typedef __attribute__((ext_vector_type(4))) float f32x4;

__device__ __forceinline__ ushort f2bf(float f) {
  __hip_bfloat16 b = __float2bfloat16(f);
  union { __hip_bfloat16 b; ushort u; } cv; cv.b = b; return cv.u;
}
__device__ __forceinline__ uint pk2(float a, float b) {
  return (uint)f2bf(a) | ((uint)f2bf(b) << 16);
}

// WA[k][0..3] = {W.att_s h0, W.att_s h1, W.att_d h0, W.att_d h1} as bf16
__global__ __launch_bounds__(128) void k_wa(const float* __restrict__ W,
                                            const float* __restrict__ as,
                                            const float* __restrict__ ad,
                                            ushort* __restrict__ wa) {
  const int k = threadIdx.x;  // 0..127
  float s0 = 0.f, s1 = 0.f, d0 = 0.f, d1 = 0.f;
  const float* wr = &W[k * 128];
  for (int c = 0; c < 64; ++c) {
    float w0 = wr[c], w1 = wr[64 + c];
    s0 = fmaf(w0, as[c], s0);
    s1 = fmaf(w1, as[64 + c], s1);
    d0 = fmaf(w0, ad[c], d0);
    d1 = fmaf(w1, ad[64 + c], d1);
  }
  wa[k * 4 + 0] = f2bf(s0);
  wa[k * 4 + 1] = f2bf(s1);
  wa[k * 4 + 2] = f2bf(d0);
  wa[k * 4 + 3] = f2bf(d1);
}

// h = x @ W via bf16 MFMA; fused a_s/a_d via WA fragment (wave 3).
__global__ __launch_bounds__(256) void k_gemm(
    const float* __restrict__ x, const float* __restrict__ W,
    const ushort* __restrict__ wa, __hip_bfloat162* __restrict__ h2,
    float* __restrict__ a_s, float* __restrict__ a_d, int Nn) {
  __shared__ ushort Al[64 * 128];  // 16 KB, XOR-swizzled bf16 x-tile
  char* lb = (char*)Al;
  const int wave = threadIdx.x >> 6;
  const int lane = threadIdx.x & 63;
  const int row0 = blockIdx.x * 64;
  const int l15 = lane & 15;
  const int kb = (lane >> 4) * 8;  // k-offset of this lane's frag elements

  // ---- stage x tile: fp32 -> bf16 LDS, swizzled ----
  {
    const int t = threadIdx.x;
    const int srow = t >> 2, q = t & 3;
    int gr = row0 + srow; gr = (gr < Nn) ? gr : (Nn - 1);
    const float4* xr = (const float4*)&x[(size_t)gr * 128 + q * 32];
#pragma unroll
    for (int i = 0; i < 4; ++i) {
      float4 v0 = xr[2 * i], v1 = xr[2 * i + 1];
      uint4 w;
      w.x = pk2(v0.x, v0.y); w.y = pk2(v0.z, v0.w);
      w.z = pk2(v1.x, v1.y); w.w = pk2(v1.z, v1.w);
      int byte = srow * 256 + ((q * 64 + i * 16) ^ ((srow & 7) << 4));
      *(uint4*)(lb + byte) = w;
    }
  }

  // ---- B fragments (W) in registers: 2 col-tiles x 4 k-steps ----
  bf16x8 bfr[2][4];
#pragma unroll
  for (int c = 0; c < 2; ++c) {
#pragma unroll
    for (int ks = 0; ks < 4; ++ks) {
      const float* wp = &W[(ks * 32 + kb) * 128 + wave * 32 + c * 16 + l15];
      union { bf16x8 v; ushort u[8]; } t;
#pragma unroll
      for (int j = 0; j < 8; ++j) t.u[j] = f2bf(wp[j * 128]);
      bfr[c][ks] = t.v;
    }
  }
  // WA fragment (wave 3 only)
  bf16x8 wafr[4];
  if (wave == 3) {
#pragma unroll
    for (int ks = 0; ks < 4; ++ks) {
      union { bf16x8 v; ushort u[8]; } t;
#pragma unroll
      for (int j = 0; j < 8; ++j)
        t.u[j] = (l15 < 4) ? wa[(ks * 32 + kb + j) * 4 + l15] : (ushort)0;
      wafr[ks] = t.v;
    }
  }

  __syncthreads();

  // ---- MFMA main loop ----
  f32x4 acc[4][2];
  f32x4 accwa[4];
#pragma unroll
  for (int r = 0; r < 4; ++r) {
    acc[r][0] = (f32x4){0.f, 0.f, 0.f, 0.f};
    acc[r][1] = (f32x4){0.f, 0.f, 0.f, 0.f};
    accwa[r] = (f32x4){0.f, 0.f, 0.f, 0.f};
  }
#pragma unroll
  for (int ks = 0; ks < 4; ++ks) {
    bf16x8 af[4];
#pragma unroll
    for (int r = 0; r < 4; ++r) {
      int row = r * 16 + l15;
      int byte = row * 256 + ((ks * 64 + (lane >> 4) * 16) ^ ((row & 7) << 4));
      uint4 v = *(const uint4*)(lb + byte);
      union { uint4 q; bf16x8 v; } cv; cv.q = v;
      af[r] = cv.v;
    }
#pragma unroll
    for (int r = 0; r < 4; ++r) {
      acc[r][0] = __builtin_amdgcn_mfma_f32_16x16x32_bf16(af[r], bfr[0][ks],
                                                          acc[r][0], 0, 0, 0);
      acc[r][1] = __builtin_amdgcn_mfma_f32_16x16x32_bf16(af[r], bfr[1][ks],
                                                          acc[r][1], 0, 0, 0);
    }
    if (wave == 3) {
#pragma unroll
      for (int r = 0; r < 4; ++r)
        accwa[r] = __builtin_amdgcn_mfma_f32_16x16x32_bf16(af[r], wafr[ks],
                                                           accwa[r], 0, 0, 0);
    }
  }

  // ---- store h (bf16, direct) ----
  ushort* hs = (ushort*)h2;
  const int rbase = (lane >> 4) * 4;
#pragma unroll
  for (int r = 0; r < 4; ++r) {
#pragma unroll
    for (int c = 0; c < 2; ++c) {
      int col = wave * 32 + c * 16 + l15;
#pragma unroll
      for (int i = 0; i < 4; ++i) {
        int grow = row0 + r * 16 + rbase + i;
        if (grow < Nn) hs[(size_t)grow * 128 + col] = f2bf(acc[r][c][i]);
      }
    }
  }
  // ---- store a_s / a_d from WA accumulators ----
  if (wave == 3) {
#pragma unroll
    for (int r = 0; r < 4; ++r) {
#pragma unroll
      for (int i = 0; i < 4; ++i) {
        int grow = row0 + r * 16 + rbase + i;
        if (grow < Nn) {
          float v = accwa[r][i];
          if (l15 < 2) a_s[grow * 2 + l15] = v;
          else if (l15 < 4) a_d[grow * 2 + (l15 - 2)] = v;
        }
      }
    }
  }
}

// per-chunk LDS histogram over buckets -> bhist[bucket][chunk]
__global__ __launch_bounds__(TH) void k_bhist(const int* __restrict__ dst,
                                              int* __restrict__ bhist, int E,
                                              int nbuck, int chunk) {
  __shared__ int hl[MAXBUCK];
  for (int i = threadIdx.x; i < nbuck; i += TH) hl[i] = 0;
  __syncthreads();
  const int s = blockIdx.x * chunk;
  const int e = (s + chunk < E) ? s + chunk : E;
  for (int i = s + threadIdx.x; i < e; i += TH)
    atomicAdd(&hl[dst[i] >> BSH], 1);
  __syncthreads();
  for (int b = threadIdx.x; b < nbuck; b += TH)
    bhist[b * NBLK + blockIdx.x] = hl[b];
}

// per bucket: exclusive scan over chunks -> raw cursors; write bucket total
__global__ __launch_bounds__(NBLK) void k_bscan(const int* __restrict__ bhist,
                                                int* __restrict__ cursors,
                                                int* __restrict__ totals,
                                                int nbuck) {
  __shared__ int tmp[NBLK];
  const int b = blockIdx.x;
  const int t = threadIdx.x;
  const int v = bhist[b * NBLK + t];
  tmp[t] = v;
  __syncthreads();
  for (int d = 1; d < NBLK; d <<= 1) {
    int add = (t >= d) ? tmp[t - d] : 0;
    __syncthreads();
    tmp[t] += add;
    __syncthreads();
  }
  cursors[t * nbuck + b] = tmp[t] - v;  // raw (no base)
  if (t == NBLK - 1) totals[b] = tmp[t];
}

// exclusive scan of bucket totals -> bases[0..nbuck]
__global__ __launch_bounds__(MAXBUCK) void k_bbase(const int* __restrict__ totals,
                                                   int* __restrict__ bases,
                                                   int nbuck) {
  __shared__ int tmp[MAXBUCK];
  const int t = threadIdx.x;
  const int v = (t < nbuck) ? totals[t] : 0;
  tmp[t] = v;
  __syncthreads();
  for (int d = 1; d < MAXBUCK; d <<= 1) {
    int add = (t >= d) ? tmp[t - d] : 0;
    __syncthreads();
    tmp[t] += add;
    __syncthreads();
  }
  if (t < nbuck) bases[t] = tmp[t] - v;
  if (t == nbuck - 1) bases[nbuck] = tmp[t];
}

// scatter packed (local_dst<<16 | src) into bucket-grouped pairs array
__global__ __launch_bounds__(TH) void k_binsert(
    const int* __restrict__ src, const int* __restrict__ dst,
    const int* __restrict__ cursors, const int* __restrict__ bases,
    int* __restrict__ pairs, int E, int nbuck, int chunk) {
  __shared__ int cur[MAXBUCK];
  for (int i = threadIdx.x; i < nbuck; i += TH)
    cur[i] = cursors[blockIdx.x * nbuck + i] + bases[i];
  __syncthreads();
  const int s = blockIdx.x * chunk;
  const int e = (s + chunk < E) ? s + chunk : E;
  for (int i = s + threadIdx.x; i < e; i += TH) {
    const int d = dst[i];
    const int b = d >> BSH;
    const int p = atomicAdd(&cur[b], 1);
    pairs[p] = ((d & (BSZ - 1)) << 16) | src[i];
  }
}

// per bucket: per-node counts + scan -> off/cnt, then LDS-atomic csr scatter
__global__ __launch_bounds__(256) void k_bucket(
    const int* __restrict__ pairs, const int* __restrict__ bases,
    int* __restrict__ off, int* __restrict__ cnt, int* __restrict__ csr,
    int Nn) {
  __shared__ int cl[BSZ];
  __shared__ int tmp[BSZ];
  __shared__ int cu[BSZ];
  const int b = blockIdx.x;
  const int t = threadIdx.x;
  const int n0 = b << BSH;
  if (t < BSZ) cl[t] = 0;
  __syncthreads();
  const int s = bases[b], e = bases[b + 1];
  for (int i = s + t; i < e; i += 256) atomicAdd(&cl[pairs[i] >> 16], 1);
  __syncthreads();
  int v = 0;
  if (t < BSZ) { v = cl[t]; tmp[t] = v; }
  __syncthreads();
  for (int d = 1; d < BSZ; d <<= 1) {
    int add = (t < BSZ && t >= d) ? tmp[t - d] : 0;
    __syncthreads();
    if (t < BSZ) tmp[t] += add;
    __syncthreads();
  }
  if (t < BSZ) {
    const int excl = tmp[t] - v;
    cu[t] = s + excl;
    const int node = n0 + t;
    if (node < Nn) { off[node] = s + excl; cnt[node] = v; }
  }
  __syncthreads();
  for (int i = s + t; i < e; i += 256) {
    const int pv = pairs[i];
    const int p = atomicAdd(&cu[pv >> 16], 1);
    csr[p] = pv & 0xffff;
  }
}

__device__ __forceinline__ float leaky02(float v) {
  return fmaxf(v, 0.2f * v);  // slope 0.2 leaky relu (valid for both signs)
}

// One wave per destination node. Max-free softmax, single edge sweep.
__global__ __launch_bounds__(256) void k_aggr(
    const __hip_bfloat162* __restrict__ h2, const float* __restrict__ a_s,
    const float* __restrict__ a_d, const int* __restrict__ off,
    const int* __restrict__ cnt, const int* __restrict__ csr,
    const float* __restrict__ bias, float* __restrict__ out, int Nn) {
  // per-wave staging: 64 edge entries of {byte_voff, w0, w1, pad}
  __shared__ uint4 ew[4][64];
  const int wave = threadIdx.x >> 6;
  const int lane = threadIdx.x & 63;
  const int d = blockIdx.x * 4 + wave;
  if (d >= Nn) return;
  const int o = off[d];
  const int deg = cnt[d];
  const float2 ad2 = *(const float2*)&a_d[d * 2];
  const char* hb = (const char*)h2;
  const unsigned l4 = lane * 4u;

  float acc0 = 0.f, acc1 = 0.f;   // this lane's 2 channels
  float sw0 = 0.f, sw1 = 0.f;     // per-lane partial esum (head0, head1)

  for (int c = 0; c < deg; c += 64) {
    int rem = deg - c; if (rem > 64) rem = 64;
    {
      unsigned voff = 0; float w0 = 0.f, w1 = 0.f;
      if (lane < rem) {
        int sl = csr[o + c + lane];
        float2 as2 = *(const float2*)&a_s[sl * 2];
        w0 = __expf(leaky02(as2.x + ad2.x));
        w1 = __expf(leaky02(as2.y + ad2.y));
        voff = (unsigned)sl << 8;  // byte offset of h2 row (256 B/row)
        sw0 += w0; sw1 += w1;
      }
      uint4 t;
      t.x = voff;
      t.y = __float_as_uint(w0);
      t.z = __float_as_uint(w1);
      t.w = 0;
      ew[wave][lane] = t;  // ds_write_b128; same-wave consumer, lgkmcnt order
    }
    int j = 0;
    for (; j + 4 <= rem; j += 4) {
      uint4 tA = ew[wave][j + 0];
      uint4 tB = ew[wave][j + 1];
      uint4 tC = ew[wave][j + 2];
      uint4 tD = ew[wave][j + 3];
      float avA = __uint_as_float((lane < 32) ? tA.y : tA.z);
      float avB = __uint_as_float((lane < 32) ? tB.y : tB.z);
      float avC = __uint_as_float((lane < 32) ? tC.y : tC.z);
      float avD = __uint_as_float((lane < 32) ? tD.y : tD.z);
      __hip_bfloat162 hA = *(const __hip_bfloat162*)(hb + (size_t)(tA.x + l4));
      __hip_bfloat162 hB = *(const __hip_bfloat162*)(hb + (size_t)(tB.x + l4));
      __hip_bfloat162 hC = *(const __hip_bfloat162*)(hb + (size_t)(tC.x + l4));
      __hip_bfloat162 hD = *(const __hip_bfloat162*)(hb + (size_t)(tD.x + l4));
      acc0 = fmaf(avA, __bfloat162float(hA.x), acc0);
      acc1 = fmaf(avA, __bfloat162float(hA.y), acc1);
      acc0 = fmaf(avB, __bfloat162float(hB.x), acc0);
      acc1 = fmaf(avB, __bfloat162float(hB.y), acc1);
      acc0 = fmaf(avC, __bfloat162float(hC.x), acc0);
      acc1 = fmaf(avC, __bfloat162float(hC.y), acc1);
      acc0 = fmaf(avD, __bfloat162float(hD.x), acc0);
      acc1 = fmaf(avD, __bfloat162float(hD.y), acc1);
    }
    for (; j < rem; ++j) {
      uint4 t = ew[wave][j];
      float av = __uint_as_float((lane < 32) ? t.y : t.z);
      __hip_bfloat162 hv = *(const __hip_bfloat162*)(hb + (size_t)(t.x + l4));
      acc0 = fmaf(av, __bfloat162float(hv.x), acc0);
      acc1 = fmaf(av, __bfloat162float(hv.y), acc1);
    }
  }
  // butterfly-reduce per-lane esum partials across the wave
#pragma unroll
  for (int msk = 1; msk <= 32; msk <<= 1) {
    sw0 += __shfl_xor(sw0, msk, 64);
    sw1 += __shfl_xor(sw1, msk, 64);
  }
  // self loop (weight computed uniformly on all lanes)
  {
    float2 as2 = *(const float2*)&a_s[d * 2];
    float w0 = __expf(leaky02(as2.x + ad2.x));
    float w1 = __expf(leaky02(as2.y + ad2.y));
    sw0 += w0; sw1 += w1;
    float av = (lane < 32) ? w0 : w1;
    __hip_bfloat162 hv = h2[(size_t)d * 64 + lane];
    acc0 = fmaf(av, __bfloat162float(hv.x), acc0);
    acc1 = fmaf(av, __bfloat162float(hv.y), acc1);
  }
  const float invsel = 1.f / (((lane < 32) ? sw0 : sw1) + 1e-16f);
  acc0 *= invsel; acc1 *= invsel;
  // head mean: lane l (<32, head0 ch 2l,2l+1) + lane l+32 (head1 ch 2l,2l+1)
  float o0 = acc0 + __shfl_down(acc0, 32, 64);
  float o1 = acc1 + __shfl_down(acc1, 32, 64);
  if (lane < 32) {
    int c = lane * 2;
    float2 res = make_float2(0.5f * o0 + bias[c], 0.5f * o1 + bias[c + 1]);
    *(float2*)&out[(size_t)d * 64 + c] = res;
  }
}

extern "C" void kernel_launch(void* const* d_in, const int* in_sizes, int n_in,
                              void* d_out, int out_size, void* d_ws,
                              size_t ws_size, hipStream_t stream) {
  const float* x = (const float*)d_in[0];
  const float* W = (const float*)d_in[1];
  const float* att_s = (const float*)d_in[2];
  const float* att_d = (const float*)d_in[3];
  const float* bias = (const float*)d_in[4];
  const int* ei = (const int*)d_in[5];
  const int Nn = in_sizes[0] / 128;
  const int E = in_sizes[5] / 2;
  const int* src = ei;
  const int* dst = ei + E;
  float* out = (float*)d_out;

  const int nbuck = (Nn + BSZ - 1) >> BSH;          // 391 for N=50000
  const int chunk = (E + NBLK - 1) / NBLK;          // 6250 for E=1.6M

  // workspace layout
  __hip_bfloat162* h2 = (__hip_bfloat162*)d_ws;     // N*64 bf16x2 (12.8MB)
  float* a_s = (float*)(h2 + (size_t)Nn * 64);      // N*2
  float* a_d = a_s + (size_t)Nn * 2;                // N*2
  int* off = (int*)(a_d + (size_t)Nn * 2);          // N
  int* cnt = off + Nn;                              // N
  int* bhist = cnt + Nn;                            // nbuck*NBLK
  int* cursors = bhist + (size_t)nbuck * NBLK;      // NBLK*nbuck
  int* totals = cursors + (size_t)NBLK * nbuck;     // nbuck
  int* bases = totals + nbuck;                      // nbuck+1
  ushort* wa = (ushort*)(bases + nbuck + 1);        // 128*4 bf16 (256 ints)
  int* pairs = (int*)(wa + 512);                    // E
  int* csr = pairs + (size_t)E;                     // E

  hipLaunchKernelGGL(k_wa, dim3(1), dim3(128), 0, stream, W, att_s, att_d, wa);
  hipLaunchKernelGGL(k_gemm, dim3((Nn + 63) / 64), dim3(256), 0, stream, x, W,
                     wa, h2, a_s, a_d, Nn);
  hipLaunchKernelGGL(k_bhist, dim3(NBLK), dim3(TH), 0, stream, dst, bhist, E,
                     nbuck, chunk);
  hipLaunchKernelGGL(k_bscan, dim3(nbuck), dim3(NBLK), 0, stream, bhist,
                     cursors, totals, nbuck);
  hipLaunchKernelGGL(k_bbase, dim3(1), dim3(MAXBUCK), 0, stream, totals, bases,
                     nbuck);
  hipLaunchKernelGGL(k_binsert, dim3(NBLK), dim3(TH), 0, stream, src, dst,
                     cursors, bases, pairs, E, nbuck, chunk);
  hipLaunchKernelGGL(k_bucket, dim3(nbuck), dim3(256), 0, stream, pairs, bases,
                     off, cnt, csr, Nn);
  hipLaunchKernelGGL(k_aggr, dim3((Nn + 3) / 4), dim3(256), 0, stream, h2, a_s,
                     a_d, off, cnt, csr, bias, out, Nn);
}

// Round 7
// 117.804 us; speedup vs baseline: 3.9225x; 1.0461x over previous
//
#include <hip/hip_runtime.h>
#include <hip/hip_bf16.h>

// ---------------------------------------------------------------------------
// GATConv (PyG-style, H=2 heads, C=64, concat=False -> head mean) on gfx950.
// Phases:
//   0. k_wa     : WA[k][4] = W @ {att_s,att_d per head}  (logits = x @ WA)
//   1. k_gemm   : h = x@W via bf16 MFMA 16x16x32. 64-row tile, x->bf16 LDS
//                 (XOR-swizzled), W-frags in registers; wave 3 contracts an
//                 extra WA fragment -> a_s/a_d directly from MFMA acc.
//   2. CSR build via two-level counting sort (no global atomics).
//   3. k_aggr   : per-dst wave, max-free softmax, single edge sweep.
//                 Head-split LDS staging: ewA={voff,w0}, ewB={voff,w1};
//                 lanes<32 read ewA, >=32 read ewB (2-way broadcast = free).
//                 One ds_read_b128 = TWO edges; 8 gathers in flight.
// ---------------------------------------------------------------------------

#define NBLK 256   // edge chunks (= threads in k_bscan)
#define TH 512     // threads for bhist/binsert
#define BSH 7      // bucket = dst >> 7
#define BSZ 128    // nodes per bucket
#define MAXBUCK 512
#define PLCAP 8192 // k_bucket LDS pair capacity (32 KB); avg bucket ~4224

typedef __attribute__((ext_vector_type(8))) short bf16x8;
typedef __attribute__((ext_vector_type(4))) float f32x4;

__device__ __forceinline__ ushort f2bf(float f) {
  __hip_bfloat16 b = __float2bfloat16(f);
  union { __hip_bfloat16 b; ushort u; } cv; cv.b = b; return cv.u;
}
__device__ __forceinline__ uint pk2(float a, float b) {
  return (uint)f2bf(a) | ((uint)f2bf(b) << 16);
}

// WA[k][0..3] = {W.att_s h0, W.att_s h1, W.att_d h0, W.att_d h1} as bf16
__global__ __launch_bounds__(128) void k_wa(const float* __restrict__ W,
                                            const float* __restrict__ as,
                                            const float* __restrict__ ad,
                                            ushort* __restrict__ wa) {
  const int k = threadIdx.x;  // 0..127
  float s0 = 0.f, s1 = 0.f, d0 = 0.f, d1 = 0.f;
  const float* wr = &W[k * 128];
  for (int c = 0; c < 64; ++c) {
    float w0 = wr[c], w1 = wr[64 + c];
    s0 = fmaf(w0, as[c], s0);
    s1 = fmaf(w1, as[64 + c], s1);
    d0 = fmaf(w0, ad[c], d0);
    d1 = fmaf(w1, ad[64 + c], d1);
  }
  wa[k * 4 + 0] = f2bf(s0);
  wa[k * 4 + 1] = f2bf(s1);
  wa[k * 4 + 2] = f2bf(d0);
  wa[k * 4 + 3] = f2bf(d1);
}

// h = x @ W via bf16 MFMA; fused a_s/a_d via WA fragment (wave 3).
__global__ __launch_bounds__(256) void k_gemm(
    const float* __restrict__ x, const float* __restrict__ W,
    const ushort* __restrict__ wa, __hip_bfloat162* __restrict__ h2,
    float* __restrict__ a_s, float* __restrict__ a_d, int Nn) {
  __shared__ ushort Al[64 * 128];  // 16 KB, XOR-swizzled bf16 x-tile
  char* lb = (char*)Al;
  const int wave = threadIdx.x >> 6;
  const int lane = threadIdx.x & 63;
  const int row0 = blockIdx.x * 64;
  const int l15 = lane & 15;
  const int kb = (lane >> 4) * 8;  // k-offset of this lane's frag elements

  // ---- stage x tile: fp32 -> bf16 LDS, swizzled ----
  {
    const int t = threadIdx.x;
    const int srow = t >> 2, q = t & 3;
    int gr = row0 + srow; gr = (gr < Nn) ? gr : (Nn - 1);
    const float4* xr = (const float4*)&x[(size_t)gr * 128 + q * 32];
#pragma unroll
    for (int i = 0; i < 4; ++i) {
      float4 v0 = xr[2 * i], v1 = xr[2 * i + 1];
      uint4 w;
      w.x = pk2(v0.x, v0.y); w.y = pk2(v0.z, v0.w);
      w.z = pk2(v1.x, v1.y); w.w = pk2(v1.z, v1.w);
      int byte = srow * 256 + ((q * 64 + i * 16) ^ ((srow & 7) << 4));
      *(uint4*)(lb + byte) = w;
    }
  }

  // ---- B fragments (W) in registers: 2 col-tiles x 4 k-steps ----
  bf16x8 bfr[2][4];
#pragma unroll
  for (int c = 0; c < 2; ++c) {
#pragma unroll
    for (int ks = 0; ks < 4; ++ks) {
      const float* wp = &W[(ks * 32 + kb) * 128 + wave * 32 + c * 16 + l15];
      union { bf16x8 v; ushort u[8]; } t;
#pragma unroll
      for (int j = 0; j < 8; ++j) t.u[j] = f2bf(wp[j * 128]);
      bfr[c][ks] = t.v;
    }
  }
  // WA fragment (wave 3 only)
  bf16x8 wafr[4];
  if (wave == 3) {
#pragma unroll
    for (int ks = 0; ks < 4; ++ks) {
      union { bf16x8 v; ushort u[8]; } t;
#pragma unroll
      for (int j = 0; j < 8; ++j)
        t.u[j] = (l15 < 4) ? wa[(ks * 32 + kb + j) * 4 + l15] : (ushort)0;
      wafr[ks] = t.v;
    }
  }

  __syncthreads();

  // ---- MFMA main loop ----
  f32x4 acc[4][2];
  f32x4 accwa[4];
#pragma unroll
  for (int r = 0; r < 4; ++r) {
    acc[r][0] = (f32x4){0.f, 0.f, 0.f, 0.f};
    acc[r][1] = (f32x4){0.f, 0.f, 0.f, 0.f};
    accwa[r] = (f32x4){0.f, 0.f, 0.f, 0.f};
  }
#pragma unroll
  for (int ks = 0; ks < 4; ++ks) {
    bf16x8 af[4];
#pragma unroll
    for (int r = 0; r < 4; ++r) {
      int row = r * 16 + l15;
      int byte = row * 256 + ((ks * 64 + (lane >> 4) * 16) ^ ((row & 7) << 4));
      uint4 v = *(const uint4*)(lb + byte);
      union { uint4 q; bf16x8 v; } cv; cv.q = v;
      af[r] = cv.v;
    }
#pragma unroll
    for (int r = 0; r < 4; ++r) {
      acc[r][0] = __builtin_amdgcn_mfma_f32_16x16x32_bf16(af[r], bfr[0][ks],
                                                          acc[r][0], 0, 0, 0);
      acc[r][1] = __builtin_amdgcn_mfma_f32_16x16x32_bf16(af[r], bfr[1][ks],
                                                          acc[r][1], 0, 0, 0);
    }
    if (wave == 3) {
#pragma unroll
      for (int r = 0; r < 4; ++r)
        accwa[r] = __builtin_amdgcn_mfma_f32_16x16x32_bf16(af[r], wafr[ks],
                                                           accwa[r], 0, 0, 0);
    }
  }

  // ---- store h (bf16, direct) ----
  ushort* hs = (ushort*)h2;
  const int rbase = (lane >> 4) * 4;
#pragma unroll
  for (int r = 0; r < 4; ++r) {
#pragma unroll
    for (int c = 0; c < 2; ++c) {
      int col = wave * 32 + c * 16 + l15;
#pragma unroll
      for (int i = 0; i < 4; ++i) {
        int grow = row0 + r * 16 + rbase + i;
        if (grow < Nn) hs[(size_t)grow * 128 + col] = f2bf(acc[r][c][i]);
      }
    }
  }
  // ---- store a_s / a_d from WA accumulators ----
  if (wave == 3) {
#pragma unroll
    for (int r = 0; r < 4; ++r) {
#pragma unroll
      for (int i = 0; i < 4; ++i) {
        int grow = row0 + r * 16 + rbase + i;
        if (grow < Nn) {
          float v = accwa[r][i];
          if (l15 < 2) a_s[grow * 2 + l15] = v;
          else if (l15 < 4) a_d[grow * 2 + (l15 - 2)] = v;
        }
      }
    }
  }
}

// per-chunk LDS histogram over buckets -> bhist[bucket][chunk]
__global__ __launch_bounds__(TH) void k_bhist(const int* __restrict__ dst,
                                              int* __restrict__ bhist, int E,
                                              int nbuck, int chunk) {
  __shared__ int hl[MAXBUCK];
  for (int i = threadIdx.x; i < nbuck; i += TH) hl[i] = 0;
  __syncthreads();
  const int s = blockIdx.x * chunk;
  const int e = (s + chunk < E) ? s + chunk : E;
  for (int i = s + threadIdx.x; i < e; i += TH)
    atomicAdd(&hl[dst[i] >> BSH], 1);
  __syncthreads();
  for (int b = threadIdx.x; b < nbuck; b += TH)
    bhist[b * NBLK + blockIdx.x] = hl[b];
}

// per bucket: exclusive scan over chunks -> raw cursors; write bucket total
__global__ __launch_bounds__(NBLK) void k_bscan(const int* __restrict__ bhist,
                                                int* __restrict__ cursors,
                                                int* __restrict__ totals,
                                                int nbuck) {
  __shared__ int tmp[NBLK];
  const int b = blockIdx.x;
  const int t = threadIdx.x;
  const int v = bhist[b * NBLK + t];
  tmp[t] = v;
  __syncthreads();
  for (int d = 1; d < NBLK; d <<= 1) {
    int add = (t >= d) ? tmp[t - d] : 0;
    __syncthreads();
    tmp[t] += add;
    __syncthreads();
  }
  cursors[t * nbuck + b] = tmp[t] - v;  // raw (no base)
  if (t == NBLK - 1) totals[b] = tmp[t];
}

// exclusive scan of bucket totals -> bases[0..nbuck]
__global__ __launch_bounds__(MAXBUCK) void k_bbase(const int* __restrict__ totals,
                                                   int* __restrict__ bases,
                                                   int nbuck) {
  __shared__ int tmp[MAXBUCK];
  const int t = threadIdx.x;
  const int v = (t < nbuck) ? totals[t] : 0;
  tmp[t] = v;
  __syncthreads();
  for (int d = 1; d < MAXBUCK; d <<= 1) {
    int add = (t >= d) ? tmp[t - d] : 0;
    __syncthreads();
    tmp[t] += add;
    __syncthreads();
  }
  if (t < nbuck) bases[t] = tmp[t] - v;
  if (t == nbuck - 1) bases[nbuck] = tmp[t];
}

// scatter packed (local_dst<<16 | src) into bucket-grouped pairs array
__global__ __launch_bounds__(TH) void k_binsert(
    const int* __restrict__ src, const int* __restrict__ dst,
    const int* __restrict__ cursors, const int* __restrict__ bases,
    int* __restrict__ pairs, int E, int nbuck, int chunk) {
  __shared__ int cur[MAXBUCK];
  for (int i = threadIdx.x; i < nbuck; i += TH)
    cur[i] = cursors[blockIdx.x * nbuck + i] + bases[i];
  __syncthreads();
  const int s = blockIdx.x * chunk;
  const int e = (s + chunk < E) ? s + chunk : E;
  for (int i = s + threadIdx.x; i < e; i += TH) {
    const int d = dst[i];
    const int b = d >> BSH;
    const int p = atomicAdd(&cur[b], 1);
    pairs[p] = ((d & (BSZ - 1)) << 16) | src[i];
  }
}

// per bucket: single-pass (pairs staged in LDS): count+scan -> off/cnt, then
// LDS-sourced scatter into csr. Fallback to two global passes if oversized.
__global__ __launch_bounds__(256) void k_bucket(
    const int* __restrict__ pairs, const int* __restrict__ bases,
    int* __restrict__ off, int* __restrict__ cnt, int* __restrict__ csr,
    int Nn) {
  __shared__ int pl[PLCAP];  // 32 KB
  __shared__ int cl[BSZ];
  __shared__ int tmp[BSZ];
  __shared__ int cu[BSZ];
  const int b = blockIdx.x;
  const int t = threadIdx.x;
  const int n0 = b << BSH;
  if (t < BSZ) cl[t] = 0;
  __syncthreads();
  const int s = bases[b], e = bases[b + 1];
  const int len = e - s;
  const bool fit = (len <= PLCAP);
  if (fit) {
    for (int i = t; i < len; i += 256) {
      int pv = pairs[s + i];
      pl[i] = pv;
      atomicAdd(&cl[pv >> 16], 1);
    }
  } else {
    for (int i = s + t; i < e; i += 256) atomicAdd(&cl[pairs[i] >> 16], 1);
  }
  __syncthreads();
  int v = 0;
  if (t < BSZ) { v = cl[t]; tmp[t] = v; }
  __syncthreads();
  for (int d = 1; d < BSZ; d <<= 1) {
    int add = (t < BSZ && t >= d) ? tmp[t - d] : 0;
    __syncthreads();
    if (t < BSZ) tmp[t] += add;
    __syncthreads();
  }
  if (t < BSZ) {
    const int excl = tmp[t] - v;
    cu[t] = s + excl;
    const int node = n0 + t;
    if (node < Nn) { off[node] = s + excl; cnt[node] = v; }
  }
  __syncthreads();
  if (fit) {
    for (int i = t; i < len; i += 256) {
      const int pv = pl[i];
      const int p = atomicAdd(&cu[pv >> 16], 1);
      csr[p] = pv & 0xffff;
    }
  } else {
    for (int i = s + t; i < e; i += 256) {
      const int pv = pairs[i];
      const int p = atomicAdd(&cu[pv >> 16], 1);
      csr[p] = pv & 0xffff;
    }
  }
}

__device__ __forceinline__ float leaky02(float v) {
  return fmaxf(v, 0.2f * v);  // slope 0.2 leaky relu (valid for both signs)
}

// One wave per destination node. Max-free softmax, single edge sweep.
// Head-split staging: ewA = {voff, w_head0}, ewB = {voff, w_head1}.
__global__ __launch_bounds__(256) void k_aggr(
    const __hip_bfloat162* __restrict__ h2, const float* __restrict__ a_s,
    const float* __restrict__ a_d, const int* __restrict__ off,
    const int* __restrict__ cnt, const int* __restrict__ csr,
    const float* __restrict__ bias, float* __restrict__ out, int Nn) {
  __shared__ uint2 ewA[4][64];  // 2 KB
  __shared__ uint2 ewB[4][64];  // 2 KB
  const int wave = threadIdx.x >> 6;
  const int lane = threadIdx.x & 63;
  const int d = blockIdx.x * 4 + wave;
  if (d >= Nn) return;
  const int o = off[d];
  const int deg = cnt[d];
  const float2 ad2 = *(const float2*)&a_d[d * 2];
  const char* hb = (const char*)h2;
  const unsigned l4 = lane * 4u;
  // half-wave-uniform base: lanes<32 read head0 entries, >=32 head1 entries
  const uint4* ebase = (lane < 32) ? (const uint4*)&ewA[wave][0]
                                   : (const uint4*)&ewB[wave][0];

  float acc0 = 0.f, acc1 = 0.f;   // this lane's 2 channels
  float sw0 = 0.f, sw1 = 0.f;     // per-lane partial esum (head0, head1)

  for (int c = 0; c < deg; c += 64) {
    int rem = deg - c; if (rem > 64) rem = 64;
    {
      unsigned voff = 0; float w0 = 0.f, w1 = 0.f;
      if (lane < rem) {
        int sl = csr[o + c + lane];
        float2 as2 = *(const float2*)&a_s[sl * 2];
        w0 = __expf(leaky02(as2.x + ad2.x));
        w1 = __expf(leaky02(as2.y + ad2.y));
        voff = (unsigned)sl << 8;  // byte offset of h2 row (256 B/row)
        sw0 += w0; sw1 += w1;
      }
      ewA[wave][lane] = make_uint2(voff, __float_as_uint(w0));
      ewB[wave][lane] = make_uint2(voff, __float_as_uint(w1));
    }
    // each uint4 = TWO edges: {voffA, wA, voffB, wB} (head-matched per lane)
    const int nq = (rem + 1) >> 1;  // odd tail edge has w=0, voff=0 (harmless)
    int q = 0;
    for (; q + 4 <= nq; q += 4) {
      uint4 p0 = ebase[q + 0];
      uint4 p1 = ebase[q + 1];
      uint4 p2 = ebase[q + 2];
      uint4 p3 = ebase[q + 3];
      __hip_bfloat162 hA0 = *(const __hip_bfloat162*)(hb + (size_t)(p0.x + l4));
      __hip_bfloat162 hB0 = *(const __hip_bfloat162*)(hb + (size_t)(p0.z + l4));
      __hip_bfloat162 hA1 = *(const __hip_bfloat162*)(hb + (size_t)(p1.x + l4));
      __hip_bfloat162 hB1 = *(const __hip_bfloat162*)(hb + (size_t)(p1.z + l4));
      __hip_bfloat162 hA2 = *(const __hip_bfloat162*)(hb + (size_t)(p2.x + l4));
      __hip_bfloat162 hB2 = *(const __hip_bfloat162*)(hb + (size_t)(p2.z + l4));
      __hip_bfloat162 hA3 = *(const __hip_bfloat162*)(hb + (size_t)(p3.x + l4));
      __hip_bfloat162 hB3 = *(const __hip_bfloat162*)(hb + (size_t)(p3.z + l4));
      acc0 = fmaf(__uint_as_float(p0.y), __bfloat162float(hA0.x), acc0);
      acc1 = fmaf(__uint_as_float(p0.y), __bfloat162float(hA0.y), acc1);
      acc0 = fmaf(__uint_as_float(p0.w), __bfloat162float(hB0.x), acc0);
      acc1 = fmaf(__uint_as_float(p0.w), __bfloat162float(hB0.y), acc1);
      acc0 = fmaf(__uint_as_float(p1.y), __bfloat162float(hA1.x), acc0);
      acc1 = fmaf(__uint_as_float(p1.y), __bfloat162float(hA1.y), acc1);
      acc0 = fmaf(__uint_as_float(p1.w), __bfloat162float(hB1.x), acc0);
      acc1 = fmaf(__uint_as_float(p1.w), __bfloat162float(hB1.y), acc1);
      acc0 = fmaf(__uint_as_float(p2.y), __bfloat162float(hA2.x), acc0);
      acc1 = fmaf(__uint_as_float(p2.y), __bfloat162float(hA2.y), acc1);
      acc0 = fmaf(__uint_as_float(p2.w), __bfloat162float(hB2.x), acc0);
      acc1 = fmaf(__uint_as_float(p2.w), __bfloat162float(hB2.y), acc1);
      acc0 = fmaf(__uint_as_float(p3.y), __bfloat162float(hA3.x), acc0);
      acc1 = fmaf(__uint_as_float(p3.y), __bfloat162float(hA3.y), acc1);
      acc0 = fmaf(__uint_as_float(p3.w), __bfloat162float(hB3.x), acc0);
      acc1 = fmaf(__uint_as_float(p3.w), __bfloat162float(hB3.y), acc1);
    }
    for (; q < nq; ++q) {
      uint4 p = ebase[q];
      __hip_bfloat162 hA = *(const __hip_bfloat162*)(hb + (size_t)(p.x + l4));
      __hip_bfloat162 hB = *(const __hip_bfloat162*)(hb + (size_t)(p.z + l4));
      acc0 = fmaf(__uint_as_float(p.y), __bfloat162float(hA.x), acc0);
      acc1 = fmaf(__uint_as_float(p.y), __bfloat162float(hA.y), acc1);
      acc0 = fmaf(__uint_as_float(p.w), __bfloat162float(hB.x), acc0);
      acc1 = fmaf(__uint_as_float(p.w), __bfloat162float(hB.y), acc1);
    }
  }
  // butterfly-reduce per-lane esum partials across the wave
#pragma unroll
  for (int msk = 1; msk <= 32; msk <<= 1) {
    sw0 += __shfl_xor(sw0, msk, 64);
    sw1 += __shfl_xor(sw1, msk, 64);
  }
  // self loop (weight computed uniformly on all lanes)
  {
    float2 as2 = *(const float2*)&a_s[d * 2];
    float w0 = __expf(leaky02(as2.x + ad2.x));
    float w1 = __expf(leaky02(as2.y + ad2.y));
    sw0 += w0; sw1 += w1;
    float av = (lane < 32) ? w0 : w1;
    __hip_bfloat162 hv = h2[(size_t)d * 64 + lane];
    acc0 = fmaf(av, __bfloat162float(hv.x), acc0);
    acc1 = fmaf(av, __bfloat162float(hv.y), acc1);
  }
  const float invsel = 1.f / (((lane < 32) ? sw0 : sw1) + 1e-16f);
  acc0 *= invsel; acc1 *= invsel;
  // head mean: lane l (<32, head0 ch 2l,2l+1) + lane l+32 (head1 ch 2l,2l+1)
  float o0 = acc0 + __shfl_down(acc0, 32, 64);
  float o1 = acc1 + __shfl_down(acc1, 32, 64);
  if (lane < 32) {
    int c = lane * 2;
    float2 res = make_float2(0.5f * o0 + bias[c], 0.5f * o1 + bias[c + 1]);
    *(float2*)&out[(size_t)d * 64 + c] = res;
  }
}

extern "C" void kernel_launch(void* const* d_in, const int* in_sizes, int n_in,
                              void* d_out, int out_size, void* d_ws,
                              size_t ws_size, hipStream_t stream) {
  const float* x = (const float*)d_in[0];
  const float* W = (const float*)d_in[1];
  const float* att_s = (const float*)d_in[2];
  const float* att_d = (const float*)d_in[3];
  const float* bias = (const float*)d_in[4];
  const int* ei = (const int*)d_in[5];
  const int Nn = in_sizes[0] / 128;
  const int E = in_sizes[5] / 2;
  const int* src = ei;
  const int* dst = ei + E;
  float* out = (float*)d_out;

  const int nbuck = (Nn + BSZ - 1) >> BSH;          // 391 for N=50000
  const int chunk = (E + NBLK - 1) / NBLK;          // 6250 for E=1.6M

  // workspace layout
  __hip_bfloat162* h2 = (__hip_bfloat162*)d_ws;     // N*64 bf16x2 (12.8MB)
  float* a_s = (float*)(h2 + (size_t)Nn * 64);      // N*2
  float* a_d = a_s + (size_t)Nn * 2;                // N*2
  int* off = (int*)(a_d + (size_t)Nn * 2);          // N
  int* cnt = off + Nn;                              // N
  int* bhist = cnt + Nn;                            // nbuck*NBLK
  int* cursors = bhist + (size_t)nbuck * NBLK;      // NBLK*nbuck
  int* totals = cursors + (size_t)NBLK * nbuck;     // nbuck
  int* bases = totals + nbuck;                      // nbuck+1
  ushort* wa = (ushort*)(bases + nbuck + 1);        // 128*4 bf16 (256 ints)
  int* pairs = (int*)(wa + 512);                    // E
  int* csr = pairs + (size_t)E;                     // E

  hipLaunchKernelGGL(k_wa, dim3(1), dim3(128), 0, stream, W, att_s, att_d, wa);
  hipLaunchKernelGGL(k_gemm, dim3((Nn + 63) / 64), dim3(256), 0, stream, x, W,
                     wa, h2, a_s, a_d, Nn);
  hipLaunchKernelGGL(k_bhist, dim3(NBLK), dim3(TH), 0, stream, dst, bhist, E,
                     nbuck, chunk);
  hipLaunchKernelGGL(k_bscan, dim3(nbuck), dim3(NBLK), 0, stream, bhist,
                     cursors, totals, nbuck);
  hipLaunchKernelGGL(k_bbase, dim3(1), dim3(MAXBUCK), 0, stream, totals, bases,
                     nbuck);
  hipLaunchKernelGGL(k_binsert, dim3(NBLK), dim3(TH), 0, stream, src, dst,
                     cursors, bases, pairs, E, nbuck, chunk);
  hipLaunchKernelGGL(k_bucket, dim3(nbuck), dim3(256), 0, stream, pairs, bases,
                     off, cnt, csr, Nn);
  hipLaunchKernelGGL(k_aggr, dim3((Nn + 3) / 4), dim3(256), 0, stream, h2, a_s,
                     a_d, off, cnt, csr, bias, out, Nn);
}